// Round 2
// baseline (1354.450 us; speedup 1.0000x reference)
//
#include <hip/hip_runtime.h>
#include <math.h>

#define NN 100000
#define NE 3200000
#define CAP 80   /* CSR slots per node; Poisson(32) => P(any node >80) ~ 1e-7; overflow falls back to atomics */

#define SQ3f   1.7320508075688772f
#define SQ5f   2.2360679774997896f
#define SQ15f  3.8729833462074170f
#define INV_SQ3f 0.57735026918962576f
#define INV_SQ5f 0.44721359549995794f
#define C_Hf   0.31622776601683794f   /* sqrt(15)/2 / sqrt(37.5) */
#define C_S5f  0.36514837167011072f   /* sqrt(5)   / sqrt(37.5) */
#define C_S5Hf 0.18257418583505536f   /* sqrt(5)/2 / sqrt(37.5) */
#define ERBF_K 0.44721359549995794f   /* sqrt(2/10) */
#define PI_OVER_CUT 0.31415926535897931f
#define INV_CUT 0.1f
#define EPSf 1e-5f

#define ERBF_OFF 48000000L   /* NN*480 */
#define ERSH_OFF 99200000L   /* +NE*16 */

typedef __attribute__((ext_vector_type(8))) short bf16x8;
typedef __attribute__((ext_vector_type(4))) float f32x4;

__device__ __forceinline__ float bf2f(unsigned short b){
  union { unsigned int u; float f; } c; c.u = ((unsigned int)b) << 16; return c.f;
}
__device__ __forceinline__ unsigned short f2bf(float f){
  union { float f; unsigned int u; } c; c.f = f;
  unsigned int u = c.u;
  return (unsigned short)((u + 0x7fffu + ((u >> 16) & 1u)) >> 16);
}
template<bool BF> __device__ __forceinline__ float ldf(const void* p, long i){
  if (BF) return bf2f(((const unsigned short*)p)[i]);
  return ((const float*)p)[i];
}
template<bool BF> __device__ __forceinline__ void stf(void* p, long i, float v){
  if (BF) ((unsigned short*)p)[i] = f2bf(v);
  else ((float*)p)[i] = v;
}
__device__ __forceinline__ float sigf(float v){ return 1.0f / (1.0f + expf(-v)); }

// vectorized gathers (memcpy -> widest load the alignment permits)
template<bool BF> __device__ __forceinline__ void ld_pos3(const void* pos, long idx, float r[3]){
  if (BF){
    const unsigned short* p = (const unsigned short*)pos + idx*3;
    unsigned int w; __builtin_memcpy(&w, p, 4);
    r[0] = bf2f((unsigned short)(w & 0xffffu));
    r[1] = bf2f((unsigned short)(w >> 16));
    r[2] = bf2f(p[2]);
  } else {
    const float* p = (const float*)pos + idx*3;
    float2 v; __builtin_memcpy(&v, p, 8);
    r[0] = v.x; r[1] = v.y; r[2] = p[2];
  }
}
template<bool BF> __device__ __forceinline__ void ld_x9(const void* x, long row, float o[9]){
  if (BF){
    const unsigned short* p = (const unsigned short*)x + row*9;
    uint4 w; __builtin_memcpy(&w, p, 16);
    o[0]=bf2f((unsigned short)(w.x & 0xffffu)); o[1]=bf2f((unsigned short)(w.x >> 16));
    o[2]=bf2f((unsigned short)(w.y & 0xffffu)); o[3]=bf2f((unsigned short)(w.y >> 16));
    o[4]=bf2f((unsigned short)(w.z & 0xffffu)); o[5]=bf2f((unsigned short)(w.z >> 16));
    o[6]=bf2f((unsigned short)(w.w & 0xffffu)); o[7]=bf2f((unsigned short)(w.w >> 16));
    o[8]=bf2f(p[8]);
  } else {
    const float* p = (const float*)x + row*9;
    float4 A, B; __builtin_memcpy(&A, p, 16); __builtin_memcpy(&B, p + 4, 16);
    o[0]=A.x; o[1]=A.y; o[2]=A.z; o[3]=A.w;
    o[4]=B.x; o[5]=B.y; o[6]=B.z; o[7]=B.w;
    o[8]=p[8];
  }
}

__device__ __forceinline__ void edge_geom(float vx, float vy, float vz,
    float& ux, float& uy, float& uz, float sh[5],
    float& g0, float& g1, float& g2, float& dist, float& rinv, float& fc)
{
  dist = sqrtf(vx*vx + vy*vy + vz*vz);
  rinv = 1.0f / fmaxf(dist, 1e-12f);
  ux = vx*rinv; uy = vy*rinv; uz = vz*rinv;
  sh[0] = SQ15f*ux*uz;
  sh[1] = SQ15f*ux*uy;
  sh[2] = SQ5f*(uy*uy - 0.5f*(ux*ux + uz*uz));
  sh[3] = SQ15f*uy*uz;
  sh[4] = 0.5f*SQ15f*(uz*uz - ux*ux);
  float d = dist * INV_CUT;
  float d2 = d*d, d5 = d2*d2*d;
  fc = 1.0f - 21.0f*d5 + 35.0f*d5*d - 15.0f*d5*d2;
  fc = (d < 1.0f) ? fc : 0.0f;
  float eg = expf(-d2);
  g0 = eg*fc; g1 = g0*d; g2 = g1*d;
}

// ---------------------------------------------------------------------------
// init: detect dtype (bf16 vs f32) from x, and compute W222 (5x5x5) in f64.
// ---------------------------------------------------------------------------
__global__ void init_kernel(const void* __restrict__ x, int* __restrict__ flag,
                            float* __restrict__ w222){
  if (threadIdx.x != 0 || blockIdx.x != 0) return;
  int isbf = 1;
  const unsigned short* p = (const unsigned short*)x;
  for (int i = 0; i < 256; i++){
    float v = bf2f(p[i]);
    if (!(fabsf(v) < 1e4f)) { isbf = 0; break; }
  }
  *flag = isbf;

  double A[5][3][3];
  for (int m = 0; m < 5; m++) for (int i = 0; i < 3; i++) for (int j = 0; j < 3; j++) A[m][i][j] = 0.0;
  const double h = 1.9364916731037085;  // sqrt(15)/2
  const double s5 = 2.2360679774997896; // sqrt(5)
  A[0][0][2] = h;  A[0][2][0] = h;
  A[1][0][1] = h;  A[1][1][0] = h;
  A[2][0][0] = -0.5*s5; A[2][1][1] = s5; A[2][2][2] = -0.5*s5;
  A[3][1][2] = h;  A[3][2][1] = h;
  A[4][0][0] = -h; A[4][2][2] = h;
  double W[125];
  for (int m = 0; m < 5; m++) for (int n = 0; n < 5; n++) for (int q = 0; q < 5; q++){
    double s = 0.0;
    for (int i = 0; i < 3; i++) for (int k = 0; k < 3; k++) for (int j = 0; j < 3; j++)
      s += A[m][i][k] * A[n][k][j] * A[q][j][i];
    W[m*25 + n*5 + q] = s;
  }
  double nrm2 = 0.0;
  double W2[125];
  for (int m = 0; m < 5; m++) for (int n = 0; n < 5; n++) for (int q = 0; q < 5; q++){
    double s = W[m*25 + n*5 + q] + W[n*25 + m*5 + q];
    W2[m*25 + n*5 + q] = s;
    nrm2 += s * s;
  }
  double inv = 1.0 / sqrt(nrm2);
  for (int i = 0; i < 125; i++) w222[i] = (float)(W2[i] * inv);
}

// ---------------------------------------------------------------------------
// pack: B-operand fragments for mfma_f32_16x16x32_bf16 (bf16 path only).
// B[k][c]: lane holds col c = nt*16 + (lane&15), k = ks*32 + (lane>>4)*8 + j.
// ---------------------------------------------------------------------------
__global__ void pack_kernel(const void* __restrict__ w0b, const void* __restrict__ w1b,
                            const void* __restrict__ w2b, const int* __restrict__ flag,
                            unsigned short* __restrict__ b0, unsigned short* __restrict__ b1,
                            unsigned short* __restrict__ b2){
  if (*flag == 0) return;
  const int tid = threadIdx.x;
  const unsigned short* s0 = (const unsigned short*)w0b;
  for (int i = tid; i < 16384; i += 256){
    int j = i & 7, lane = (i>>3)&63, nt = (i>>9)&7, ks = i>>12;
    int k = ks*32 + (lane>>4)*8 + j, c = nt*16 + (lane&15);
    b0[i] = s0[k*128 + c];
  }
  const unsigned short* s1 = (const unsigned short*)w1b;
  for (int i = tid; i < 4096; i += 256){
    int j = i & 7, lane = (i>>3)&63, nt = (i>>9)&3, ks = i>>11;
    int k = ks*32 + (lane>>4)*8 + j, c = nt*16 + (lane&15);
    b1[i] = s1[k*64 + c];
  }
  const unsigned short* s2 = (const unsigned short*)w2b;
  for (int i = tid; i < 1024; i += 256){
    int j = i & 7, lane = (i>>3)&63, nt = (i>>9)&1;
    int k = (lane>>4)*8 + j, c = nt*16 + (lane&15);
    b2[i] = s2[k*32 + c];
  }
}

// ---------------------------------------------------------------------------
// Edge kernel: build CSR (1 int atomic/edge), write erbf/ersh.
// ---------------------------------------------------------------------------
template<bool BF>
__global__ __launch_bounds__(256) void edge_kernel(
    const void* __restrict__ x, const void* __restrict__ pos, const int* __restrict__ ei,
    const int* __restrict__ flag, int* __restrict__ cnt, int* __restrict__ csr,
    float* __restrict__ a, void* __restrict__ out)
{
  if ((*flag != 0) != BF) return;
  const int e = blockIdx.x * 256 + threadIdx.x;
  const int src = ei[e], dst = ei[NE + e];
  float sp[3], dp[3];
  ld_pos3<BF>(pos, src, sp);
  ld_pos3<BF>(pos, dst, dp);
  // permutation: new (x,y,z) = (pos1, pos2, pos0)
  float vx = dp[1]-sp[1], vy = dp[2]-sp[2], vz = dp[0]-sp[0];
  float ux, uy, uz, sh[5], g0, g1, g2, dist, rinv, fc;
  edge_geom(vx, vy, vz, ux, uy, uz, sh, g0, g1, g2, dist, rinv, fc);

  int slot = atomicAdd(&cnt[dst], 1);
  if (slot < CAP){
    csr[(long)dst*CAP + slot] = src;
  } else {
    float xr[9]; ld_x9<BF>(x, src, xr);
    float* ad = a + (long)dst * 9;
    atomicAdd(ad + 0, xr[0] * g0);
    atomicAdd(ad + 1, xr[1] * (SQ3f*ux) * g1);
    atomicAdd(ad + 2, xr[2] * (SQ3f*uy) * g1);
    atomicAdd(ad + 3, xr[3] * (SQ3f*uz) * g1);
    atomicAdd(ad + 4, xr[4] * sh[0] * g2);
    atomicAdd(ad + 5, xr[5] * sh[1] * g2);
    atomicAdd(ad + 6, xr[6] * sh[2] * g2);
    atomicAdd(ad + 7, xr[7] * sh[3] * g2);
    atomicAdd(ad + 8, xr[8] * sh[4] * g2);
  }

  float t = PI_OVER_CUT * dist;
  float st = sinf(t), c2t = 2.0f*cosf(t);
  float kk = ERBF_K * fc * rinv;
  float snm1 = 0.0f, sn = st;
  if (BF){
    unsigned short eb[16];
    #pragma unroll
    for (int n = 0; n < 16; n++){
      eb[n] = f2bf(sn * kk);
      float nx = c2t*sn - snm1; snm1 = sn; sn = nx;
    }
    uint4* q = (uint4*)((unsigned short*)out + ERBF_OFF + (long)e*16);
    q[0] = make_uint4((unsigned)eb[0] | ((unsigned)eb[1] << 16),
                      (unsigned)eb[2] | ((unsigned)eb[3] << 16),
                      (unsigned)eb[4] | ((unsigned)eb[5] << 16),
                      (unsigned)eb[6] | ((unsigned)eb[7] << 16));
    q[1] = make_uint4((unsigned)eb[8]  | ((unsigned)eb[9]  << 16),
                      (unsigned)eb[10] | ((unsigned)eb[11] << 16),
                      (unsigned)eb[12] | ((unsigned)eb[13] << 16),
                      (unsigned)eb[14] | ((unsigned)eb[15] << 16));
  } else {
    float er[16];
    #pragma unroll
    for (int n = 0; n < 16; n++){
      er[n] = sn * kk;
      float nx = c2t*sn - snm1; snm1 = sn; sn = nx;
    }
    float4* q = (float4*)((float*)out + ERBF_OFF + (long)e*16);
    q[0] = make_float4(er[0], er[1], er[2], er[3]);
    q[1] = make_float4(er[4], er[5], er[6], er[7]);
    q[2] = make_float4(er[8], er[9], er[10], er[11]);
    q[3] = make_float4(er[12], er[13], er[14], er[15]);
  }
  long sb = ERSH_OFF + (long)e*9;
  stf<BF>(out, sb + 0, 1.0f);
  stf<BF>(out, sb + 1, -SQ3f*ux);
  stf<BF>(out, sb + 2, -SQ3f*uy);
  stf<BF>(out, sb + 3, -SQ3f*uz);
  stf<BF>(out, sb + 4, sh[0]);
  stf<BF>(out, sb + 5, sh[1]);
  stf<BF>(out, sb + 6, sh[2]);
  stf<BF>(out, sb + 7, sh[3]);
  stf<BF>(out, sb + 8, sh[4]);
}

// ---------------------------------------------------------------------------
// Aggregation: one wave per node; gather+recompute+reduce; zero atomics.
// ---------------------------------------------------------------------------
template<bool BF>
__global__ __launch_bounds__(256) void agg_kernel(
    const void* __restrict__ x, const void* __restrict__ pos,
    const int* __restrict__ flag, const int* __restrict__ cnt,
    const int* __restrict__ csr, float* __restrict__ a)
{
  if ((*flag != 0) != BF) return;
  const int tid = threadIdx.x;
  const int n = blockIdx.x * 4 + (tid >> 6);
  const int lane = tid & 63;
  float dp[3]; ld_pos3<BF>(pos, n, dp);
  int cn = cnt[n];
  int cc = cn < CAP ? cn : CAP;
  float acc[9];
  #pragma unroll
  for (int j = 0; j < 9; j++) acc[j] = 0.f;
  for (int slot = lane; slot < cc; slot += 64){
    int src = csr[(long)n*CAP + slot];
    float sp[3]; ld_pos3<BF>(pos, src, sp);
    float xr[9]; ld_x9<BF>(x, src, xr);
    float vx = dp[1]-sp[1], vy = dp[2]-sp[2], vz = dp[0]-sp[0];
    float ux, uy, uz, sh[5], g0, g1, g2, dist, rinv, fc;
    edge_geom(vx, vy, vz, ux, uy, uz, sh, g0, g1, g2, dist, rinv, fc);
    acc[0] += xr[0] * g0;
    acc[1] += xr[1] * (SQ3f*ux) * g1;
    acc[2] += xr[2] * (SQ3f*uy) * g1;
    acc[3] += xr[3] * (SQ3f*uz) * g1;
    acc[4] += xr[4] * sh[0] * g2;
    acc[5] += xr[5] * sh[1] * g2;
    acc[6] += xr[6] * sh[2] * g2;
    acc[7] += xr[7] * sh[3] * g2;
    acc[8] += xr[8] * sh[4] * g2;
  }
  #pragma unroll
  for (int j = 0; j < 9; j++){
    #pragma unroll
    for (int off = 32; off > 0; off >>= 1)
      acc[j] += __shfl_xor(acc[j], off, 64);
  }
  if (lane == 0){
    float* an = a + (long)n * 9;
    #pragma unroll
    for (int j = 0; j < 9; j++) an[j] += acc[j];
  }
}

// ===========================================================================
// MFMA c-kernels (bf16 path). A-tile (activations) in swizzled LDS bf16;
// B-frags pre-packed in ws. mfma_f32_16x16x32_bf16:
//   A: row=lane&15, k=(lane>>4)*8+j ; B: col=lane&15, k=(lane>>4)*8+j
//   C: col=lane&15, row=(lane>>4)*4+j
// LDS swizzle: byte ^= (row&7)<<4 (chunk-of-16B permute within row).
// ===========================================================================

// ---- C0: 64 nodes/block; H[64][128]=sigmoid(o0@W0a); C=H@W0b -> out[0,128)
__global__ __launch_bounds__(256) void c0_mfma(const float* __restrict__ a,
    const void* __restrict__ tp, const void* __restrict__ w0a,
    const unsigned short* __restrict__ b0, const int* __restrict__ flag,
    void* __restrict__ out, float* __restrict__ stats)
{
  if (*flag == 0) return;
  __shared__ float W0aL[384];
  __shared__ float o0L[192];
  __shared__ unsigned short Hs[64*128];   // 16KB, rows 256B, swizzled
  __shared__ float sumL[128], sqL[128];
  const int tid = threadIdx.x;
  const int n0 = blockIdx.x * 64;
  for (int i = tid; i < 384; i += 256) W0aL[i] = ldf<true>(w0a, i);
  if (tid < 128){ sumL[tid] = 0.f; sqL[tid] = 0.f; }
  if (tid < 192){
    int n = tid / 3, j = tid - n*3;
    float v = 0.f;
    if (n0 + n < NN){
      const float* an = a + (long)(n0 + n) * 9;
      float tpj = ldf<true>(tp, j);
      if (j == 0)      v = tpj * an[0]*an[0];
      else if (j == 1) v = tpj * (an[1]*an[1] + an[2]*an[2] + an[3]*an[3]) * INV_SQ3f;
      else             v = tpj * (an[4]*an[4] + an[5]*an[5] + an[6]*an[6] + an[7]*an[7] + an[8]*an[8]) * INV_SQ5f;
    }
    o0L[tid] = v;
  }
  __syncthreads();
  {
    const int cp = tid & 63, nb = tid >> 6;
    #pragma unroll
    for (int it = 0; it < 16; it++){
      int n = it*4 + nb;
      float q0 = o0L[n*3], q1 = o0L[n*3+1], q2 = o0L[n*3+2];
      int c = cp*2;
      float p0 = q0*W0aL[c]   + q1*W0aL[128+c]   + q2*W0aL[256+c];
      float p1 = q0*W0aL[c+1] + q1*W0aL[128+c+1] + q2*W0aL[256+c+1];
      unsigned int pk = (unsigned)f2bf(sigf(p0)) | ((unsigned)f2bf(sigf(p1)) << 16);
      int byt = n*256 + ((c*2) ^ ((n&7)<<4));
      *(unsigned int*)((char*)Hs + byt) = pk;
    }
  }
  __syncthreads();
  const int lane = tid & 63, wv = tid >> 6;
  const int hi = lane >> 4, col = lane & 15;
  bf16x8 afr[4];
  #pragma unroll
  for (int ks = 0; ks < 4; ks++){
    int row = wv*16 + (lane & 15);
    int byt = row*256 + ((ks*64 + hi*16) ^ ((row&7)<<4));
    afr[ks] = *(const bf16x8*)((const char*)Hs + byt);
  }
  for (int nt = 0; nt < 8; nt++){
    f32x4 acc = {0.f, 0.f, 0.f, 0.f};
    #pragma unroll
    for (int ks = 0; ks < 4; ks++){
      bf16x8 bfr = *(const bf16x8*)(b0 + ((long)(ks*8 + nt)*64 + lane)*8);
      acc = __builtin_amdgcn_mfma_f32_16x16x32_bf16(afr[ks], bfr, acc, 0, 0, 0);
    }
    int ch = nt*16 + col;
    float s = 0.f, sq = 0.f;
    #pragma unroll
    for (int j = 0; j < 4; j++){
      int g = n0 + wv*16 + hi*4 + j;
      if (g < NN){
        stf<true>(out, (long)g*480 + ch, acc[j]);
        s += acc[j]; sq += acc[j]*acc[j];
      }
    }
    atomicAdd(&sumL[ch], s);
    atomicAdd(&sqL[ch], sq);
  }
  __syncthreads();
  if (tid < 128){ atomicAdd(&stats[tid], sumL[tid]); atomicAdd(&stats[128 + tid], sqL[tid]); }
}

// ---- C1: rows r=m*64+n (192 rows, K=64, N=64) -> out[128,320)
__global__ __launch_bounds__(256) void c1_mfma(const float* __restrict__ a,
    const void* __restrict__ tp, const void* __restrict__ w1a,
    const unsigned short* __restrict__ b1, const int* __restrict__ flag,
    void* __restrict__ out, float* __restrict__ stats1)
{
  if (*flag == 0) return;
  __shared__ float W1aL[256];
  __shared__ float o1L[64*12];
  __shared__ unsigned short Hs[192*64];   // 24KB, rows 128B, swizzled
  __shared__ float ssL[64];
  const int tid = threadIdx.x;
  const int n0 = blockIdx.x * 64;
  for (int i = tid; i < 256; i += 256) W1aL[i] = ldf<true>(w1a, i);
  if (tid < 64) ssL[tid] = 0.f;
  float tp3 = ldf<true>(tp, 3), tp4 = ldf<true>(tp, 4), tp5 = ldf<true>(tp, 5), tp6 = ldf<true>(tp, 6);
  for (int idx = tid; idx < 768; idx += 256){
    int n = idx / 12, r = idx - n*12;
    int u = r / 3, m = r - u*3;
    float val = 0.f;
    if (n0 + n < NN){
      const float* an = a + (long)(n0 + n) * 9;
      float s1x = an[1], s1y = an[2], s1z = an[3];
      if (u == 0)      val = tp3 * an[0] * an[1 + m];
      else if (u == 1) val = tp4 * an[1 + m] * an[0];
      else {
        float e1m;
        if (m == 0)      e1m = C_Hf*(an[4]*s1z + an[5]*s1y - an[8]*s1x) - C_S5Hf*an[6]*s1x;
        else if (m == 1) e1m = C_Hf*(an[5]*s1x + an[7]*s1z) + C_S5f*an[6]*s1y;
        else             e1m = C_Hf*(an[4]*s1x + an[7]*s1y + an[8]*s1z) - C_S5Hf*an[6]*s1z;
        val = (u == 2 ? tp5 : tp6) * e1m;
      }
    }
    o1L[idx] = val;
  }
  __syncthreads();
  {
    const int v = tid & 63, nb = tid >> 6;
    #pragma unroll
    for (int it = 0; it < 16; it++){
      int n = it*4 + nb;
      float h0 = 0.f, h1 = 0.f, h2 = 0.f;
      #pragma unroll
      for (int u = 0; u < 4; u++){
        float w = W1aL[u*64 + v];
        h0 += o1L[n*12 + u*3 + 0]*w;
        h1 += o1L[n*12 + u*3 + 1]*w;
        h2 += o1L[n*12 + u*3 + 2]*w;
      }
      float g = sigf(sqrtf(h0*h0 + h1*h1 + h2*h2));
      unsigned short e0 = f2bf(h0*g), e1 = f2bf(h1*g), e2 = f2bf(h2*g);
      int r0 = n,       b0y = r0*128 + ((v*2) ^ ((r0&7)<<4));
      int r1 = 64 + n,  b1y = r1*128 + ((v*2) ^ ((r1&7)<<4));
      int r2 = 128 + n, b2y = r2*128 + ((v*2) ^ ((r2&7)<<4));
      *(unsigned short*)((char*)Hs + b0y) = e0;
      *(unsigned short*)((char*)Hs + b1y) = e1;
      *(unsigned short*)((char*)Hs + b2y) = e2;
    }
  }
  __syncthreads();
  const int lane = tid & 63, wv = tid >> 6;
  const int hi = lane >> 4, col = lane & 15;
  for (int mi = 0; mi < 3; mi++){
    int mt = wv*3 + mi;
    bf16x8 afr[2];
    #pragma unroll
    for (int ks = 0; ks < 2; ks++){
      int row = mt*16 + (lane & 15);
      int byt = row*128 + ((ks*64 + hi*16) ^ ((row&7)<<4));
      afr[ks] = *(const bf16x8*)((const char*)Hs + byt);
    }
    int m = mt >> 2, nlb = (mt & 3)*16;
    for (int nt = 0; nt < 4; nt++){
      f32x4 acc = {0.f, 0.f, 0.f, 0.f};
      #pragma unroll
      for (int ks = 0; ks < 2; ks++){
        bf16x8 bfr = *(const bf16x8*)(b1 + ((long)(ks*4 + nt)*64 + lane)*8);
        acc = __builtin_amdgcn_mfma_f32_16x16x32_bf16(afr[ks], bfr, acc, 0, 0, 0);
      }
      int v = nt*16 + col;
      float ssl = 0.f;
      #pragma unroll
      for (int j = 0; j < 4; j++){
        int g = n0 + nlb + hi*4 + j;
        if (g < NN){
          stf<true>(out, (long)g*480 + 128 + v*3 + m, acc[j]);
          ssl += acc[j]*acc[j];
        }
      }
      atomicAdd(&ssL[v], ssl);
    }
  }
  __syncthreads();
  if (tid < 64) atomicAdd(&stats1[tid], ssL[tid]);
}

// ---- C2: rows r=m*64+n (320 rows, K=32, N=32) -> out[320,480)
__global__ __launch_bounds__(256) void c2_mfma(const float* __restrict__ a,
    const void* __restrict__ tp, const void* __restrict__ w2a,
    const unsigned short* __restrict__ b2, const int* __restrict__ flag,
    void* __restrict__ out, float* __restrict__ stats2,
    const float* __restrict__ w222)
{
  if (*flag == 0) return;
  __shared__ float W2aL[128];
  __shared__ float o2L[64*20];
  __shared__ unsigned short Hs[320*32];   // 20KB, rows 64B, swizzled (row&3)
  __shared__ float ssL[32];
  const int tid = threadIdx.x;
  const int n0 = blockIdx.x * 64;
  for (int i = tid; i < 128; i += 256) W2aL[i] = ldf<true>(w2a, i);
  if (tid < 32) ssL[tid] = 0.f;
  float tp7 = ldf<true>(tp, 7), tp8 = ldf<true>(tp, 8), tp9 = ldf<true>(tp, 9), tp10 = ldf<true>(tp, 10);
  for (int idx = tid; idx < 1280; idx += 256){
    int n = idx / 20, r = idx - n*20, u = r / 5, m = r - u*5;
    float val = 0.f;
    if (n0 + n < NN){
      const float* an = a + (long)(n0 + n) * 9;
      float x1 = an[1], y1 = an[2], z1 = an[3];
      if (u == 0)      val = tp7 * an[0] * an[4 + m];
      else if (u == 1) val = tp8 * an[4 + m] * an[0];
      else if (u == 2){
        float pm;
        if (m == 0)      pm = 2.f*C_Hf*x1*z1;
        else if (m == 1) pm = 2.f*C_Hf*x1*y1;
        else if (m == 2) pm = C_S5f*y1*y1 - C_S5Hf*(x1*x1 + z1*z1);
        else if (m == 3) pm = 2.f*C_Hf*y1*z1;
        else             pm = C_Hf*(z1*z1 - x1*x1);
        val = tp9 * pm;
      } else {
        float q = 0.f;
        #pragma unroll
        for (int aa = 0; aa < 5; aa++){
          float sa = an[4 + aa];
          #pragma unroll
          for (int bb = 0; bb < 5; bb++) q += w222[aa*25 + bb*5 + m] * sa * an[4 + bb];
        }
        val = tp10 * q;
      }
    }
    o2L[idx] = val;
  }
  __syncthreads();
  {
    const int v = tid & 31, nb = tid >> 5;
    #pragma unroll
    for (int it = 0; it < 8; it++){
      int n = it*8 + nb;
      float h[5];
      #pragma unroll
      for (int m = 0; m < 5; m++){
        float s = 0.f;
        #pragma unroll
        for (int u = 0; u < 4; u++) s += o2L[n*20 + u*5 + m] * W2aL[u*32 + v];
        h[m] = s;
      }
      float g = sigf(sqrtf(h[0]*h[0] + h[1]*h[1] + h[2]*h[2] + h[3]*h[3] + h[4]*h[4]));
      #pragma unroll
      for (int m = 0; m < 5; m++){
        int r = m*64 + n;
        int byt = r*64 + ((v*2) ^ ((r&3)<<4));
        *(unsigned short*)((char*)Hs + byt) = f2bf(h[m]*g);
      }
    }
  }
  __syncthreads();
  const int lane = tid & 63, wv = tid >> 6;
  const int hi = lane >> 4, col = lane & 15;
  for (int mi = 0; mi < 5; mi++){
    int mt = wv*5 + mi;
    bf16x8 afr;
    {
      int row = mt*16 + (lane & 15);
      int byt = row*64 + ((hi*16) ^ ((row&3)<<4));
      afr = *(const bf16x8*)((const char*)Hs + byt);
    }
    int m = mt >> 2, nlb = (mt & 3)*16;
    for (int nt = 0; nt < 2; nt++){
      f32x4 acc = {0.f, 0.f, 0.f, 0.f};
      bf16x8 bfr = *(const bf16x8*)(b2 + ((long)nt*64 + lane)*8);
      acc = __builtin_amdgcn_mfma_f32_16x16x32_bf16(afr, bfr, acc, 0, 0, 0);
      int v = nt*16 + col;
      float ssl = 0.f;
      #pragma unroll
      for (int j = 0; j < 4; j++){
        int g = n0 + nlb + hi*4 + j;
        if (g < NN){
          stf<true>(out, (long)g*480 + 320 + v*5 + m, acc[j]);
          ssl += acc[j]*acc[j];
        }
      }
      atomicAdd(&ssL[v], ssl);
    }
  }
  __syncthreads();
  if (tid < 32) atomicAdd(&stats2[tid], ssL[tid]);
}

// ===========================================================================
// f32 fallback c-kernels (unchanged from verified version)
// ===========================================================================
template<bool BF>
__global__ __launch_bounds__(256) void c0_kernel(const float* __restrict__ a,
    const void* __restrict__ tp, const void* __restrict__ w0a, const void* __restrict__ w0b,
    const int* __restrict__ flag, void* __restrict__ out, float* __restrict__ stats)
{
  if ((*flag != 0) != BF) return;
  __shared__ float W0aL[384];
  __shared__ float W0bL[16384];
  __shared__ float h0L[16*128];
  __shared__ float o0L[16*3];
  __shared__ float sumL[128], sqL[128];
  const int tid = threadIdx.x;
  const int c = tid & 127, half = tid >> 7;
  const int n0 = blockIdx.x * 16;
  for (int i = tid; i < 384; i += 256) W0aL[i] = ldf<BF>(w0a, i);
  for (int i = tid; i < 16384; i += 256) W0bL[i] = ldf<BF>(w0b, i);
  if (tid < 128){ sumL[tid] = 0.f; sqL[tid] = 0.f; }
  if (tid < 48){
    int n = tid / 3, j = tid - n*3;
    const float* an = a + (long)(n0 + n) * 9;
    float tpj = ldf<BF>(tp, j);
    float v;
    if (j == 0)      v = tpj * an[0]*an[0];
    else if (j == 1) v = tpj * (an[1]*an[1] + an[2]*an[2] + an[3]*an[3]) * INV_SQ3f;
    else             v = tpj * (an[4]*an[4] + an[5]*an[5] + an[6]*an[6] + an[7]*an[7] + an[8]*an[8]) * INV_SQ5f;
    o0L[tid] = v;
  }
  __syncthreads();
  #pragma unroll
  for (int i = 0; i < 8; i++){
    int n = half*8 + i;
    float pre = o0L[n*3]*W0aL[c] + o0L[n*3+1]*W0aL[128+c] + o0L[n*3+2]*W0aL[256+c];
    h0L[n*128 + c] = sigf(pre);
  }
  __syncthreads();
  float acc[8];
  #pragma unroll
  for (int i = 0; i < 8; i++) acc[i] = 0.f;
  for (int k = 0; k < 128; k++){
    float w = W0bL[k*128 + c];
    #pragma unroll
    for (int i = 0; i < 8; i++) acc[i] += h0L[(half*8 + i)*128 + k] * w;
  }
  float lsum = 0.f, lsq = 0.f;
  #pragma unroll
  for (int i = 0; i < 8; i++){
    int n = half*8 + i;
    stf<BF>(out, (long)(n0 + n)*480 + c, acc[i]);
    lsum += acc[i]; lsq += acc[i]*acc[i];
  }
  atomicAdd(&sumL[c], lsum); atomicAdd(&sqL[c], lsq);
  __syncthreads();
  if (tid < 128){ atomicAdd(&stats[tid], sumL[tid]); atomicAdd(&stats[128 + tid], sqL[tid]); }
}

template<bool BF>
__global__ __launch_bounds__(256) void c1_kernel(const float* __restrict__ a,
    const void* __restrict__ tp, const void* __restrict__ w1a, const void* __restrict__ w1b,
    const int* __restrict__ flag, void* __restrict__ out, float* __restrict__ stats1)
{
  if ((*flag != 0) != BF) return;
  __shared__ float W1aL[256];
  __shared__ float W1bL[4096];
  __shared__ float h1L[32*64*3];
  __shared__ float o1L[32*12];
  __shared__ float ssL[64];
  const int tid = threadIdx.x;
  const int v = tid & 63, ng = tid >> 6;
  const int n0 = blockIdx.x * 32;
  for (int i = tid; i < 256; i += 256) W1aL[i] = ldf<BF>(w1a, i);
  for (int i = tid; i < 4096; i += 256) W1bL[i] = ldf<BF>(w1b, i);
  if (tid < 64) ssL[tid] = 0.f;
  float tp3 = ldf<BF>(tp, 3), tp4 = ldf<BF>(tp, 4), tp5 = ldf<BF>(tp, 5), tp6 = ldf<BF>(tp, 6);
  for (int idx = tid; idx < 384; idx += 256){
    int n = idx / 12, r = idx - n*12;
    int u = r / 3, m = r - u*3;
    const float* an = a + (long)(n0 + n) * 9;
    float s1x = an[1], s1y = an[2], s1z = an[3];
    float val;
    if (u == 0)      val = tp3 * an[0] * an[1 + m];
    else if (u == 1) val = tp4 * an[1 + m] * an[0];
    else {
      float e1m;
      if (m == 0)      e1m = C_Hf*(an[4]*s1z + an[5]*s1y - an[8]*s1x) - C_S5Hf*an[6]*s1x;
      else if (m == 1) e1m = C_Hf*(an[5]*s1x + an[7]*s1z) + C_S5f*an[6]*s1y;
      else             e1m = C_Hf*(an[4]*s1x + an[7]*s1y + an[8]*s1z) - C_S5Hf*an[6]*s1z;
      val = (u == 2 ? tp5 : tp6) * e1m;
    }
    o1L[idx] = val;
  }
  __syncthreads();
  #pragma unroll
  for (int i = 0; i < 8; i++){
    int n = ng*8 + i;
    float h[3];
    #pragma unroll
    for (int m = 0; m < 3; m++){
      float s = 0.f;
      #pragma unroll
      for (int u = 0; u < 4; u++) s += o1L[n*12 + u*3 + m] * W1aL[u*64 + v];
      h[m] = s;
    }
    float g = sigf(sqrtf(h[0]*h[0] + h[1]*h[1] + h[2]*h[2]));
    int b = (n*64 + v)*3;
    h1L[b] = h[0]*g; h1L[b+1] = h[1]*g; h1L[b+2] = h[2]*g;
  }
  __syncthreads();
  float ss = 0.f;
  for (int i = 0; i < 8; i++){
    int n = ng*8 + i;
    float a0 = 0.f, a1 = 0.f, a2 = 0.f;
    for (int u = 0; u < 64; u++){
      float w = W1bL[u*64 + v];
      const float* hp = &h1L[(n*64 + u)*3];
      a0 += hp[0]*w; a1 += hp[1]*w; a2 += hp[2]*w;
    }
    long b = (long)(n0 + n)*480 + 128 + v*3;
    stf<BF>(out, b, a0); stf<BF>(out, b+1, a1); stf<BF>(out, b+2, a2);
    ss += a0*a0 + a1*a1 + a2*a2;
  }
  atomicAdd(&ssL[v], ss);
  __syncthreads();
  if (tid < 64) atomicAdd(&stats1[tid], ssL[tid]);
}

template<bool BF>
__global__ __launch_bounds__(256) void c2_kernel(const float* __restrict__ a,
    const void* __restrict__ tp, const void* __restrict__ w2a, const void* __restrict__ w2b,
    const int* __restrict__ flag, void* __restrict__ out, float* __restrict__ stats2,
    const float* __restrict__ w222)
{
  if ((*flag != 0) != BF) return;
  __shared__ float W2aL[128];
  __shared__ float W2bL[1024];
  __shared__ float h2L[32*32*5];
  __shared__ float o2L[32*20];
  __shared__ float ssL[32];
  const int tid = threadIdx.x;
  const int v = tid & 31, ng = tid >> 5;
  const int n0 = blockIdx.x * 32;
  for (int i = tid; i < 128; i += 256) W2aL[i] = ldf<BF>(w2a, i);
  for (int i = tid; i < 1024; i += 256) W2bL[i] = ldf<BF>(w2b, i);
  if (tid < 32) ssL[tid] = 0.f;
  float tp7 = ldf<BF>(tp, 7), tp8 = ldf<BF>(tp, 8), tp9 = ldf<BF>(tp, 9), tp10 = ldf<BF>(tp, 10);
  for (int idx = tid; idx < 640; idx += 256){
    int n = idx / 20, r = idx - n*20, u = r / 5, m = r - u*5;
    const float* an = a + (long)(n0 + n) * 9;
    float x1 = an[1], y1 = an[2], z1 = an[3];
    float val;
    if (u == 0)      val = tp7 * an[0] * an[4 + m];
    else if (u == 1) val = tp8 * an[4 + m] * an[0];
    else if (u == 2){
      float pm;
      if (m == 0)      pm = 2.f*C_Hf*x1*z1;
      else if (m == 1) pm = 2.f*C_Hf*x1*y1;
      else if (m == 2) pm = C_S5f*y1*y1 - C_S5Hf*(x1*x1 + z1*z1);
      else if (m == 3) pm = 2.f*C_Hf*y1*z1;
      else             pm = C_Hf*(z1*z1 - x1*x1);
      val = tp9 * pm;
    } else {
      float q = 0.f;
      #pragma unroll
      for (int aa = 0; aa < 5; aa++){
        float sa = an[4 + aa];
        #pragma unroll
        for (int bb = 0; bb < 5; bb++) q += w222[aa*25 + bb*5 + m] * sa * an[4 + bb];
      }
      val = tp10 * q;
    }
    o2L[idx] = val;
  }
  __syncthreads();
  #pragma unroll
  for (int i = 0; i < 4; i++){
    int n = ng*4 + i;
    float h[5];
    #pragma unroll
    for (int m = 0; m < 5; m++){
      float s = 0.f;
      #pragma unroll
      for (int u = 0; u < 4; u++) s += o2L[n*20 + u*5 + m] * W2aL[u*32 + v];
      h[m] = s;
    }
    float g = sigf(sqrtf(h[0]*h[0] + h[1]*h[1] + h[2]*h[2] + h[3]*h[3] + h[4]*h[4]));
    int b = (n*32 + v)*5;
    #pragma unroll
    for (int m = 0; m < 5; m++) h2L[b + m] = h[m]*g;
  }
  __syncthreads();
  float ss = 0.f;
  #pragma unroll
  for (int i = 0; i < 4; i++){
    int n = ng*4 + i;
    float acc[5] = {0.f, 0.f, 0.f, 0.f, 0.f};
    for (int u = 0; u < 32; u++){
      float w = W2bL[u*32 + v];
      const float* hp = &h2L[(n*32 + u)*5];
      #pragma unroll
      for (int m = 0; m < 5; m++) acc[m] += hp[m]*w;
    }
    long b = (long)(n0 + n)*480 + 320 + v*5;
    #pragma unroll
    for (int m = 0; m < 5; m++) stf<BF>(out, b + m, acc[m]);
    #pragma unroll
    for (int m = 0; m < 5; m++) ss += acc[m]*acc[m];
  }
  atomicAdd(&ssL[v], ss);
  __syncthreads();
  if (tid < 32) atomicAdd(&stats2[tid], ssL[tid]);
}

// ---------------------------------------------------------------------------
__global__ void finalize_kernel(const float* __restrict__ stats, float* __restrict__ params){
  int t = threadIdx.x;
  if (t < 128){
    float mean = stats[t] * (1.0f/NN);
    float var  = stats[128 + t] * (1.0f/NN) - mean*mean;
    params[t] = mean;
    params[128 + t] = 1.0f / sqrtf(fmaxf(var, 0.f) + EPSf);
  }
  if (t < 64) params[256 + t] = 1.0f / sqrtf(stats[256 + t] * (1.0f/(NN*3.0f)) + EPSf);
  if (t < 32) params[320 + t] = 1.0f / sqrtf(stats[320 + t] * (1.0f/(NN*5.0f)) + EPSf);
}

template<bool BF>
__global__ __launch_bounds__(256) void norm_kernel(const int* __restrict__ flag,
    void* __restrict__ out, const float* __restrict__ params)
{
  if ((*flag != 0) != BF) return;
  const long n = blockIdx.x;
  const int t = threadIdx.x;
  if (t >= 240) return;
  const int j = t*2;
  float v0, v1;
  if (BF){
    unsigned int w = *((const unsigned int*)out + n*240 + t);
    v0 = bf2f((unsigned short)(w & 0xffffu));
    v1 = bf2f((unsigned short)(w >> 16));
  } else {
    float2 w = *((const float2*)out + n*240 + t);
    v0 = w.x; v1 = w.y;
  }
  float r0, r1;
  if (j < 128)      r0 = (v0 - params[j]) * params[128 + j];
  else if (j < 320) r0 = v0 * params[256 + (j - 128)/3];
  else              r0 = v0 * params[320 + (j - 320)/5];
  int j1 = j + 1;
  if (j1 < 128)      r1 = (v1 - params[j1]) * params[128 + j1];
  else if (j1 < 320) r1 = v1 * params[256 + (j1 - 128)/3];
  else               r1 = v1 * params[320 + (j1 - 320)/5];
  if (BF){
    unsigned int w = (unsigned)f2bf(r0) | ((unsigned)f2bf(r1) << 16);
    *((unsigned int*)out + n*240 + t) = w;
  } else {
    *((float2*)out + n*240 + t) = make_float2(r0, r1);
  }
}

// ---------------------------------------------------------------------------
extern "C" void kernel_launch(void* const* d_in, const int* in_sizes, int n_in,
                              void* d_out, int out_size, void* d_ws, size_t ws_size,
                              hipStream_t stream) {
  const void* x   = d_in[0];
  const void* pos = d_in[1];
  const int*  ei  = (const int*)d_in[2];
  const void* tp  = d_in[3];
  const void* w0a = d_in[4];
  const void* w1a = d_in[5];
  const void* w2a = d_in[6];
  const void* w0b = d_in[7];
  const void* w1b = d_in[8];
  const void* w2b = d_in[9];

  // ws layout: [0,4) flag | [64, 400064) cnt (NN int) | [400064, 4000064) a (NN*9 f32)
  //          | [4000064,...) stats(352) | params(352) | w222(125) | @4003392 bfrag packs
  int*   flag   = (int*)d_ws;
  int*   cnt    = (int*)((char*)d_ws + 64);
  float* a      = (float*)((char*)d_ws + 400064);
  float* stats  = (float*)((char*)d_ws + 4000064);
  float* params = stats + 352;
  float* w222   = params + 352;
  unsigned short* b0 = (unsigned short*)((char*)d_ws + 4003392);
  unsigned short* b1 = b0 + 16384;
  unsigned short* b2 = b1 + 4096;

  // CSR scratch lives in d_out's node region (32MB < node region), overwritten later.
  int* csr = (int*)d_out;

  hipMemsetAsync(d_ws, 0, 4001472, stream);
  init_kernel<<<1, 64, 0, stream>>>(x, flag, w222);
  pack_kernel<<<1, 256, 0, stream>>>(w0b, w1b, w2b, flag, b0, b1, b2);

  edge_kernel<true ><<<NE/256, 256, 0, stream>>>(x, pos, ei, flag, cnt, csr, a, d_out);
  edge_kernel<false><<<NE/256, 256, 0, stream>>>(x, pos, ei, flag, cnt, csr, a, d_out);

  agg_kernel<true ><<<NN/4, 256, 0, stream>>>(x, pos, flag, cnt, csr, a);
  agg_kernel<false><<<NN/4, 256, 0, stream>>>(x, pos, flag, cnt, csr, a);

  // bf16 path: MFMA kernels (64 nodes/block, 1563 blocks covers 100000)
  c0_mfma<<<1563, 256, 0, stream>>>(a, tp, w0a, b0, flag, d_out, stats);
  c1_mfma<<<1563, 256, 0, stream>>>(a, tp, w1a, b1, flag, d_out, stats + 256);
  c2_mfma<<<1563, 256, 0, stream>>>(a, tp, w2a, b2, flag, d_out, stats + 320, w222);

  // f32 fallback path (unchanged)
  c0_kernel<false><<<NN/16, 256, 0, stream>>>(a, tp, w0a, w0b, flag, d_out, stats);
  c1_kernel<false><<<NN/32, 256, 0, stream>>>(a, tp, w1a, w1b, flag, d_out, stats + 256);
  c2_kernel<false><<<NN/32, 256, 0, stream>>>(a, tp, w2a, w2b, flag, d_out, stats + 320, w222);

  finalize_kernel<<<1, 128, 0, stream>>>(stats, params);

  norm_kernel<true ><<<NN, 256, 0, stream>>>(flag, d_out, params);
  norm_kernel<false><<<NN, 256, 0, stream>>>(flag, d_out, params);
}

// Round 3
// 1284.916 us; speedup vs baseline: 1.0541x; 1.0541x over previous
//
#include <hip/hip_runtime.h>
#include <math.h>

#define NN 100000
#define NE 3200000
#define CAP 80   /* CSR slots per node; Poisson(32) => P(any node >80) ~ 1e-7; overflow falls back to atomics */

#define SQ3f   1.7320508075688772f
#define SQ5f   2.2360679774997896f
#define SQ15f  3.8729833462074170f
#define INV_SQ3f 0.57735026918962576f
#define INV_SQ5f 0.44721359549995794f
#define C_Hf   0.31622776601683794f   /* sqrt(15)/2 / sqrt(37.5) */
#define C_S5f  0.36514837167011072f   /* sqrt(5)   / sqrt(37.5) */
#define C_S5Hf 0.18257418583505536f   /* sqrt(5)/2 / sqrt(37.5) */
#define ERBF_K 0.44721359549995794f   /* sqrt(2/10) */
#define PI_OVER_CUT 0.31415926535897931f
#define INV_CUT 0.1f
#define EPSf 1e-5f

#define ERBF_OFF 48000000L   /* NN*480 */
#define ERSH_OFF 99200000L   /* +NE*16 */

#define NB_C 1563            /* blocks per c-section: 64 nodes/block */

typedef __attribute__((ext_vector_type(8))) short bf16x8;
typedef __attribute__((ext_vector_type(4))) float f32x4;

__device__ __forceinline__ float bf2f(unsigned short b){
  union { unsigned int u; float f; } c; c.u = ((unsigned int)b) << 16; return c.f;
}
__device__ __forceinline__ unsigned short f2bf(float f){
  union { float f; unsigned int u; } c; c.f = f;
  unsigned int u = c.u;
  return (unsigned short)((u + 0x7fffu + ((u >> 16) & 1u)) >> 16);
}
template<bool BF> __device__ __forceinline__ float ldf(const void* p, long i){
  if (BF) return bf2f(((const unsigned short*)p)[i]);
  return ((const float*)p)[i];
}
template<bool BF> __device__ __forceinline__ void stf(void* p, long i, float v){
  if (BF) ((unsigned short*)p)[i] = f2bf(v);
  else ((float*)p)[i] = v;
}
__device__ __forceinline__ float sigf(float v){ return 1.0f / (1.0f + expf(-v)); }

// vectorized gathers
template<bool BF> __device__ __forceinline__ void ld_pos3(const void* pos, long idx, float r[3]){
  if (BF){
    const unsigned short* p = (const unsigned short*)pos + idx*3;
    unsigned int w; __builtin_memcpy(&w, p, 4);
    r[0] = bf2f((unsigned short)(w & 0xffffu));
    r[1] = bf2f((unsigned short)(w >> 16));
    r[2] = bf2f(p[2]);
  } else {
    const float* p = (const float*)pos + idx*3;
    float2 v; __builtin_memcpy(&v, p, 8);
    r[0] = v.x; r[1] = v.y; r[2] = p[2];
  }
}
template<bool BF> __device__ __forceinline__ void ld_x9(const void* x, long row, float o[9]){
  if (BF){
    const unsigned short* p = (const unsigned short*)x + row*9;
    uint4 w; __builtin_memcpy(&w, p, 16);
    o[0]=bf2f((unsigned short)(w.x & 0xffffu)); o[1]=bf2f((unsigned short)(w.x >> 16));
    o[2]=bf2f((unsigned short)(w.y & 0xffffu)); o[3]=bf2f((unsigned short)(w.y >> 16));
    o[4]=bf2f((unsigned short)(w.z & 0xffffu)); o[5]=bf2f((unsigned short)(w.z >> 16));
    o[6]=bf2f((unsigned short)(w.w & 0xffffu)); o[7]=bf2f((unsigned short)(w.w >> 16));
    o[8]=bf2f(p[8]);
  } else {
    const float* p = (const float*)x + row*9;
    float4 A, B; __builtin_memcpy(&A, p, 16); __builtin_memcpy(&B, p + 4, 16);
    o[0]=A.x; o[1]=A.y; o[2]=A.z; o[3]=A.w;
    o[4]=B.x; o[5]=B.y; o[6]=B.z; o[7]=B.w;
    o[8]=p[8];
  }
}

__device__ __forceinline__ void edge_geom(float vx, float vy, float vz,
    float& ux, float& uy, float& uz, float sh[5],
    float& g0, float& g1, float& g2, float& dist, float& rinv, float& fc)
{
  dist = sqrtf(vx*vx + vy*vy + vz*vz);
  rinv = 1.0f / fmaxf(dist, 1e-12f);
  ux = vx*rinv; uy = vy*rinv; uz = vz*rinv;
  sh[0] = SQ15f*ux*uz;
  sh[1] = SQ15f*ux*uy;
  sh[2] = SQ5f*(uy*uy - 0.5f*(ux*ux + uz*uz));
  sh[3] = SQ15f*uy*uz;
  sh[4] = 0.5f*SQ15f*(uz*uz - ux*ux);
  float d = dist * INV_CUT;
  float d2 = d*d, d5 = d2*d2*d;
  fc = 1.0f - 21.0f*d5 + 35.0f*d5*d - 15.0f*d5*d2;
  fc = (d < 1.0f) ? fc : 0.0f;
  float eg = expf(-d2);
  g0 = eg*fc; g1 = g0*d; g2 = g1*d;
}

// ---------------------------------------------------------------------------
// setup: dtype flag + W222 (thread 0) ; then pack MFMA B-fragments (all threads)
// ---------------------------------------------------------------------------
__global__ void setup_kernel(const void* __restrict__ x, int* __restrict__ flag,
                             float* __restrict__ w222,
                             const void* __restrict__ w0b, const void* __restrict__ w1b,
                             const void* __restrict__ w2b,
                             unsigned short* __restrict__ b0, unsigned short* __restrict__ b1,
                             unsigned short* __restrict__ b2){
  __shared__ int shf;
  const int tid = threadIdx.x;
  if (tid == 0){
    int isbf = 1;
    const unsigned short* p = (const unsigned short*)x;
    for (int i = 0; i < 256; i++){
      float v = bf2f(p[i]);
      if (!(fabsf(v) < 1e4f)) { isbf = 0; break; }
    }
    *flag = isbf;
    shf = isbf;

    double A[5][3][3];
    for (int m = 0; m < 5; m++) for (int i = 0; i < 3; i++) for (int j = 0; j < 3; j++) A[m][i][j] = 0.0;
    const double h = 1.9364916731037085;  // sqrt(15)/2
    const double s5 = 2.2360679774997896; // sqrt(5)
    A[0][0][2] = h;  A[0][2][0] = h;
    A[1][0][1] = h;  A[1][1][0] = h;
    A[2][0][0] = -0.5*s5; A[2][1][1] = s5; A[2][2][2] = -0.5*s5;
    A[3][1][2] = h;  A[3][2][1] = h;
    A[4][0][0] = -h; A[4][2][2] = h;
    double W[125];
    for (int m = 0; m < 5; m++) for (int n = 0; n < 5; n++) for (int q = 0; q < 5; q++){
      double s = 0.0;
      for (int i = 0; i < 3; i++) for (int k = 0; k < 3; k++) for (int j = 0; j < 3; j++)
        s += A[m][i][k] * A[n][k][j] * A[q][j][i];
      W[m*25 + n*5 + q] = s;
    }
    double nrm2 = 0.0;
    double W2[125];
    for (int m = 0; m < 5; m++) for (int n = 0; n < 5; n++) for (int q = 0; q < 5; q++){
      double s = W[m*25 + n*5 + q] + W[n*25 + m*5 + q];
      W2[m*25 + n*5 + q] = s;
      nrm2 += s * s;
    }
    double inv = 1.0 / sqrt(nrm2);
    for (int i = 0; i < 125; i++) w222[i] = (float)(W2[i] * inv);
  }
  __syncthreads();
  if (shf == 0) return;   // f32 path never uses MFMA fragments
  const unsigned short* s0 = (const unsigned short*)w0b;
  for (int i = tid; i < 16384; i += 256){
    int j = i & 7, lane = (i>>3)&63, nt = (i>>9)&7, ks = i>>12;
    int k = ks*32 + (lane>>4)*8 + j, c = nt*16 + (lane&15);
    b0[i] = s0[k*128 + c];
  }
  const unsigned short* s1 = (const unsigned short*)w1b;
  for (int i = tid; i < 4096; i += 256){
    int j = i & 7, lane = (i>>3)&63, nt = (i>>9)&3, ks = i>>11;
    int k = ks*32 + (lane>>4)*8 + j, c = nt*16 + (lane&15);
    b1[i] = s1[k*64 + c];
  }
  const unsigned short* s2 = (const unsigned short*)w2b;
  for (int i = tid; i < 1024; i += 256){
    int j = i & 7, lane = (i>>3)&63, nt = (i>>9)&1;
    int k = (lane>>4)*8 + j, c = nt*16 + (lane&15);
    b2[i] = s2[k*32 + c];
  }
}

// ---------------------------------------------------------------------------
// Edge: build CSR (1 int atomic/edge), write erbf/ersh. Single launch, uniform
// scalar branch on dtype flag.
// ---------------------------------------------------------------------------
template<bool BF>
__device__ __forceinline__ void edge_body(
    const void* __restrict__ x, const void* __restrict__ pos, const int* __restrict__ ei,
    int* __restrict__ cnt, int* __restrict__ csr,
    float* __restrict__ a, void* __restrict__ out)
{
  const int e = blockIdx.x * 256 + threadIdx.x;
  const int src = ei[e], dst = ei[NE + e];
  float sp[3], dp[3];
  ld_pos3<BF>(pos, src, sp);
  ld_pos3<BF>(pos, dst, dp);
  // permutation: new (x,y,z) = (pos1, pos2, pos0)
  float vx = dp[1]-sp[1], vy = dp[2]-sp[2], vz = dp[0]-sp[0];
  float ux, uy, uz, sh[5], g0, g1, g2, dist, rinv, fc;
  edge_geom(vx, vy, vz, ux, uy, uz, sh, g0, g1, g2, dist, rinv, fc);

  int slot = atomicAdd(&cnt[dst], 1);
  if (slot < CAP){
    csr[(long)dst*CAP + slot] = src;
  } else {
    float xr[9]; ld_x9<BF>(x, src, xr);
    float* ad = a + (long)dst * 9;
    atomicAdd(ad + 0, xr[0] * g0);
    atomicAdd(ad + 1, xr[1] * (SQ3f*ux) * g1);
    atomicAdd(ad + 2, xr[2] * (SQ3f*uy) * g1);
    atomicAdd(ad + 3, xr[3] * (SQ3f*uz) * g1);
    atomicAdd(ad + 4, xr[4] * sh[0] * g2);
    atomicAdd(ad + 5, xr[5] * sh[1] * g2);
    atomicAdd(ad + 6, xr[6] * sh[2] * g2);
    atomicAdd(ad + 7, xr[7] * sh[3] * g2);
    atomicAdd(ad + 8, xr[8] * sh[4] * g2);
  }

  // erbf via Chebyshev recurrence
  float t = PI_OVER_CUT * dist;
  float st = sinf(t), c2t = 2.0f*cosf(t);
  float kk = ERBF_K * fc * rinv;
  float snm1 = 0.0f, sn = st;
  if (BF){
    unsigned short eb[16];
    #pragma unroll
    for (int n = 0; n < 16; n++){
      eb[n] = f2bf(sn * kk);
      float nx = c2t*sn - snm1; snm1 = sn; sn = nx;
    }
    uint4* q = (uint4*)((unsigned short*)out + ERBF_OFF + (long)e*16);
    q[0] = make_uint4((unsigned)eb[0] | ((unsigned)eb[1] << 16),
                      (unsigned)eb[2] | ((unsigned)eb[3] << 16),
                      (unsigned)eb[4] | ((unsigned)eb[5] << 16),
                      (unsigned)eb[6] | ((unsigned)eb[7] << 16));
    q[1] = make_uint4((unsigned)eb[8]  | ((unsigned)eb[9]  << 16),
                      (unsigned)eb[10] | ((unsigned)eb[11] << 16),
                      (unsigned)eb[12] | ((unsigned)eb[13] << 16),
                      (unsigned)eb[14] | ((unsigned)eb[15] << 16));
  } else {
    float er[16];
    #pragma unroll
    for (int n = 0; n < 16; n++){
      er[n] = sn * kk;
      float nx = c2t*sn - snm1; snm1 = sn; sn = nx;
    }
    float4* q = (float4*)((float*)out + ERBF_OFF + (long)e*16);
    q[0] = make_float4(er[0], er[1], er[2], er[3]);
    q[1] = make_float4(er[4], er[5], er[6], er[7]);
    q[2] = make_float4(er[8], er[9], er[10], er[11]);
    q[3] = make_float4(er[12], er[13], er[14], er[15]);
  }
  long sb = ERSH_OFF + (long)e*9;
  stf<BF>(out, sb + 0, 1.0f);
  stf<BF>(out, sb + 1, -SQ3f*ux);
  stf<BF>(out, sb + 2, -SQ3f*uy);
  stf<BF>(out, sb + 3, -SQ3f*uz);
  stf<BF>(out, sb + 4, sh[0]);
  stf<BF>(out, sb + 5, sh[1]);
  stf<BF>(out, sb + 6, sh[2]);
  stf<BF>(out, sb + 7, sh[3]);
  stf<BF>(out, sb + 8, sh[4]);
}

__global__ __launch_bounds__(256) void edge_kernel(
    const void* __restrict__ x, const void* __restrict__ pos, const int* __restrict__ ei,
    const int* __restrict__ flag, int* __restrict__ cnt, int* __restrict__ csr,
    float* __restrict__ a, void* __restrict__ out)
{
  if (*flag) edge_body<true >(x, pos, ei, cnt, csr, a, out);
  else       edge_body<false>(x, pos, ei, cnt, csr, a, out);
}

// ---------------------------------------------------------------------------
// Aggregation: one wave per node; gather+recompute+reduce; zero atomics.
// ---------------------------------------------------------------------------
template<bool BF>
__device__ __forceinline__ void agg_body(
    const void* __restrict__ x, const void* __restrict__ pos,
    const int* __restrict__ cnt, const int* __restrict__ csr,
    float* __restrict__ a)
{
  const int tid = threadIdx.x;
  const int n = blockIdx.x * 4 + (tid >> 6);
  const int lane = tid & 63;
  float dp[3]; ld_pos3<BF>(pos, n, dp);
  int cn = cnt[n];
  int cc = cn < CAP ? cn : CAP;
  float acc[9];
  #pragma unroll
  for (int j = 0; j < 9; j++) acc[j] = 0.f;
  for (int slot = lane; slot < cc; slot += 64){
    int src = csr[(long)n*CAP + slot];
    float sp[3]; ld_pos3<BF>(pos, src, sp);
    float xr[9]; ld_x9<BF>(x, src, xr);
    float vx = dp[1]-sp[1], vy = dp[2]-sp[2], vz = dp[0]-sp[0];
    float ux, uy, uz, sh[5], g0, g1, g2, dist, rinv, fc;
    edge_geom(vx, vy, vz, ux, uy, uz, sh, g0, g1, g2, dist, rinv, fc);
    acc[0] += xr[0] * g0;
    acc[1] += xr[1] * (SQ3f*ux) * g1;
    acc[2] += xr[2] * (SQ3f*uy) * g1;
    acc[3] += xr[3] * (SQ3f*uz) * g1;
    acc[4] += xr[4] * sh[0] * g2;
    acc[5] += xr[5] * sh[1] * g2;
    acc[6] += xr[6] * sh[2] * g2;
    acc[7] += xr[7] * sh[3] * g2;
    acc[8] += xr[8] * sh[4] * g2;
  }
  #pragma unroll
  for (int j = 0; j < 9; j++){
    #pragma unroll
    for (int off = 32; off > 0; off >>= 1)
      acc[j] += __shfl_xor(acc[j], off, 64);
  }
  if (lane == 0){
    float* an = a + (long)n * 9;
    #pragma unroll
    for (int j = 0; j < 9; j++) an[j] += acc[j];
  }
}

__global__ __launch_bounds__(256) void agg_kernel(
    const void* __restrict__ x, const void* __restrict__ pos,
    const int* __restrict__ flag, const int* __restrict__ cnt,
    const int* __restrict__ csr, float* __restrict__ a)
{
  if (*flag) agg_body<true >(x, pos, cnt, csr, a);
  else       agg_body<false>(x, pos, cnt, csr, a);
}

// ===========================================================================
// Fused MFMA c-kernel (bf16 path). One launch: blocks [0,NB_C)=c0,
// [NB_C,2NB_C)=c1, [2NB_C,3NB_C)=c2. Shared memory carved from one pool.
// mfma_f32_16x16x32_bf16: A row=lane&15,k=(lane>>4)*8+j; B col=lane&15,same k;
// C col=lane&15,row=(lane>>4)*4+j.  LDS swizzle: byte ^= (row&7)<<4.
// ===========================================================================
__device__ void c0_body(int bid, const float* __restrict__ a,
    const void* __restrict__ tp, const void* __restrict__ w0a,
    const unsigned short* __restrict__ b0,
    void* __restrict__ out, float* __restrict__ stats, char* smem)
{
  float* W0aL = (float*)smem;               // 384 f
  float* o0L  = (float*)(smem + 1536);      // 192 f
  float* sumL = (float*)(smem + 2304);      // 128 f
  float* sqL  = (float*)(smem + 2816);      // 128 f
  unsigned short* Hs = (unsigned short*)(smem + 3328);  // 64*128 bf16, rows 256B
  const int tid = threadIdx.x;
  const int n0 = bid * 64;
  for (int i = tid; i < 384; i += 256) W0aL[i] = ldf<true>(w0a, i);
  if (tid < 128){ sumL[tid] = 0.f; sqL[tid] = 0.f; }
  if (tid < 192){
    int n = tid / 3, j = tid - n*3;
    float v = 0.f;
    if (n0 + n < NN){
      const float* an = a + (long)(n0 + n) * 9;
      float tpj = ldf<true>(tp, j);
      if (j == 0)      v = tpj * an[0]*an[0];
      else if (j == 1) v = tpj * (an[1]*an[1] + an[2]*an[2] + an[3]*an[3]) * INV_SQ3f;
      else             v = tpj * (an[4]*an[4] + an[5]*an[5] + an[6]*an[6] + an[7]*an[7] + an[8]*an[8]) * INV_SQ5f;
    }
    o0L[tid] = v;
  }
  __syncthreads();
  {
    const int cp = tid & 63, nb = tid >> 6;
    #pragma unroll
    for (int it = 0; it < 16; it++){
      int n = it*4 + nb;
      float q0 = o0L[n*3], q1 = o0L[n*3+1], q2 = o0L[n*3+2];
      int c = cp*2;
      float p0 = q0*W0aL[c]   + q1*W0aL[128+c]   + q2*W0aL[256+c];
      float p1 = q0*W0aL[c+1] + q1*W0aL[128+c+1] + q2*W0aL[256+c+1];
      unsigned int pk = (unsigned)f2bf(sigf(p0)) | ((unsigned)f2bf(sigf(p1)) << 16);
      int byt = n*256 + ((c*2) ^ ((n&7)<<4));
      *(unsigned int*)((char*)Hs + byt) = pk;
    }
  }
  __syncthreads();
  const int lane = tid & 63, wv = tid >> 6;
  const int hi = lane >> 4, col = lane & 15;
  bf16x8 afr[4];
  #pragma unroll
  for (int ks = 0; ks < 4; ks++){
    int row = wv*16 + (lane & 15);
    int byt = row*256 + ((ks*64 + hi*16) ^ ((row&7)<<4));
    afr[ks] = *(const bf16x8*)((const char*)Hs + byt);
  }
  for (int nt = 0; nt < 8; nt++){
    f32x4 acc = {0.f, 0.f, 0.f, 0.f};
    #pragma unroll
    for (int ks = 0; ks < 4; ks++){
      bf16x8 bfr = *(const bf16x8*)(b0 + ((long)(ks*8 + nt)*64 + lane)*8);
      acc = __builtin_amdgcn_mfma_f32_16x16x32_bf16(afr[ks], bfr, acc, 0, 0, 0);
    }
    int ch = nt*16 + col;
    float s = 0.f, sq = 0.f;
    #pragma unroll
    for (int j = 0; j < 4; j++){
      int g = n0 + wv*16 + hi*4 + j;
      if (g < NN){
        stf<true>(out, (long)g*480 + ch, acc[j]);
        s += acc[j]; sq += acc[j]*acc[j];
      }
    }
    atomicAdd(&sumL[ch], s);
    atomicAdd(&sqL[ch], sq);
  }
  __syncthreads();
  if (tid < 128){ atomicAdd(&stats[tid], sumL[tid]); atomicAdd(&stats[128 + tid], sqL[tid]); }
}

__device__ void c1_body(int bid, const float* __restrict__ a,
    const void* __restrict__ tp, const void* __restrict__ w1a,
    const unsigned short* __restrict__ b1,
    void* __restrict__ out, float* __restrict__ stats1, char* smem)
{
  float* W1aL = (float*)smem;               // 256 f
  float* o1L  = (float*)(smem + 1024);      // 768 f
  float* ssL  = (float*)(smem + 4096);      // 64 f
  unsigned short* Hs = (unsigned short*)(smem + 4352);  // 192*64 bf16, rows 128B
  const int tid = threadIdx.x;
  const int n0 = bid * 64;
  for (int i = tid; i < 256; i += 256) W1aL[i] = ldf<true>(w1a, i);
  if (tid < 64) ssL[tid] = 0.f;
  float tp3 = ldf<true>(tp, 3), tp4 = ldf<true>(tp, 4), tp5 = ldf<true>(tp, 5), tp6 = ldf<true>(tp, 6);
  for (int idx = tid; idx < 768; idx += 256){
    int n = idx / 12, r = idx - n*12;
    int u = r / 3, m = r - u*3;
    float val = 0.f;
    if (n0 + n < NN){
      const float* an = a + (long)(n0 + n) * 9;
      float s1x = an[1], s1y = an[2], s1z = an[3];
      if (u == 0)      val = tp3 * an[0] * an[1 + m];
      else if (u == 1) val = tp4 * an[1 + m] * an[0];
      else {
        float e1m;
        if (m == 0)      e1m = C_Hf*(an[4]*s1z + an[5]*s1y - an[8]*s1x) - C_S5Hf*an[6]*s1x;
        else if (m == 1) e1m = C_Hf*(an[5]*s1x + an[7]*s1z) + C_S5f*an[6]*s1y;
        else             e1m = C_Hf*(an[4]*s1x + an[7]*s1y + an[8]*s1z) - C_S5Hf*an[6]*s1z;
        val = (u == 2 ? tp5 : tp6) * e1m;
      }
    }
    o1L[idx] = val;
  }
  __syncthreads();
  {
    const int v = tid & 63, nb = tid >> 6;
    #pragma unroll
    for (int it = 0; it < 16; it++){
      int n = it*4 + nb;
      float h0 = 0.f, h1 = 0.f, h2 = 0.f;
      #pragma unroll
      for (int u = 0; u < 4; u++){
        float w = W1aL[u*64 + v];
        h0 += o1L[n*12 + u*3 + 0]*w;
        h1 += o1L[n*12 + u*3 + 1]*w;
        h2 += o1L[n*12 + u*3 + 2]*w;
      }
      float g = sigf(sqrtf(h0*h0 + h1*h1 + h2*h2));
      unsigned short e0 = f2bf(h0*g), e1 = f2bf(h1*g), e2 = f2bf(h2*g);
      int r0 = n,       b0y = r0*128 + ((v*2) ^ ((r0&7)<<4));
      int r1 = 64 + n,  b1y = r1*128 + ((v*2) ^ ((r1&7)<<4));
      int r2 = 128 + n, b2y = r2*128 + ((v*2) ^ ((r2&7)<<4));
      *(unsigned short*)((char*)Hs + b0y) = e0;
      *(unsigned short*)((char*)Hs + b1y) = e1;
      *(unsigned short*)((char*)Hs + b2y) = e2;
    }
  }
  __syncthreads();
  const int lane = tid & 63, wv = tid >> 6;
  const int hi = lane >> 4, col = lane & 15;
  for (int mi = 0; mi < 3; mi++){
    int mt = wv*3 + mi;
    bf16x8 afr[2];
    #pragma unroll
    for (int ks = 0; ks < 2; ks++){
      int row = mt*16 + (lane & 15);
      int byt = row*128 + ((ks*64 + hi*16) ^ ((row&7)<<4));
      afr[ks] = *(const bf16x8*)((const char*)Hs + byt);
    }
    int m = mt >> 2, nlb = (mt & 3)*16;
    for (int nt = 0; nt < 4; nt++){
      f32x4 acc = {0.f, 0.f, 0.f, 0.f};
      #pragma unroll
      for (int ks = 0; ks < 2; ks++){
        bf16x8 bfr = *(const bf16x8*)(b1 + ((long)(ks*4 + nt)*64 + lane)*8);
        acc = __builtin_amdgcn_mfma_f32_16x16x32_bf16(afr[ks], bfr, acc, 0, 0, 0);
      }
      int v = nt*16 + col;
      float ssl = 0.f;
      #pragma unroll
      for (int j = 0; j < 4; j++){
        int g = n0 + nlb + hi*4 + j;
        if (g < NN){
          stf<true>(out, (long)g*480 + 128 + v*3 + m, acc[j]);
          ssl += acc[j]*acc[j];
        }
      }
      atomicAdd(&ssL[v], ssl);
    }
  }
  __syncthreads();
  if (tid < 64) atomicAdd(&stats1[tid], ssL[tid]);
}

__device__ void c2_body(int bid, const float* __restrict__ a,
    const void* __restrict__ tp, const void* __restrict__ w2a,
    const unsigned short* __restrict__ b2,
    void* __restrict__ out, float* __restrict__ stats2,
    const float* __restrict__ w222, char* smem)
{
  float* W2aL = (float*)smem;               // 128 f
  float* o2L  = (float*)(smem + 512);       // 1280 f
  float* ssL  = (float*)(smem + 5632);      // 32 f
  unsigned short* Hs = (unsigned short*)(smem + 5760);  // 320*32 bf16, rows 64B
  const int tid = threadIdx.x;
  const int n0 = bid * 64;
  for (int i = tid; i < 128; i += 256) W2aL[i] = ldf<true>(w2a, i);
  if (tid < 32) ssL[tid] = 0.f;
  float tp7 = ldf<true>(tp, 7), tp8 = ldf<true>(tp, 8), tp9 = ldf<true>(tp, 9), tp10 = ldf<true>(tp, 10);
  for (int idx = tid; idx < 1280; idx += 256){
    int n = idx / 20, r = idx - n*20, u = r / 5, m = r - u*5;
    float val = 0.f;
    if (n0 + n < NN){
      const float* an = a + (long)(n0 + n) * 9;
      float x1 = an[1], y1 = an[2], z1 = an[3];
      if (u == 0)      val = tp7 * an[0] * an[4 + m];
      else if (u == 1) val = tp8 * an[4 + m] * an[0];
      else if (u == 2){
        float pm;
        if (m == 0)      pm = 2.f*C_Hf*x1*z1;
        else if (m == 1) pm = 2.f*C_Hf*x1*y1;
        else if (m == 2) pm = C_S5f*y1*y1 - C_S5Hf*(x1*x1 + z1*z1);
        else if (m == 3) pm = 2.f*C_Hf*y1*z1;
        else             pm = C_Hf*(z1*z1 - x1*x1);
        val = tp9 * pm;
      } else {
        float q = 0.f;
        #pragma unroll
        for (int aa = 0; aa < 5; aa++){
          float sa = an[4 + aa];
          #pragma unroll
          for (int bb = 0; bb < 5; bb++) q += w222[aa*25 + bb*5 + m] * sa * an[4 + bb];
        }
        val = tp10 * q;
      }
    }
    o2L[idx] = val;
  }
  __syncthreads();
  {
    const int v = tid & 31, nb = tid >> 5;
    #pragma unroll
    for (int it = 0; it < 8; it++){
      int n = it*8 + nb;
      float h[5];
      #pragma unroll
      for (int m = 0; m < 5; m++){
        float s = 0.f;
        #pragma unroll
        for (int u = 0; u < 4; u++) s += o2L[n*20 + u*5 + m] * W2aL[u*32 + v];
        h[m] = s;
      }
      float g = sigf(sqrtf(h[0]*h[0] + h[1]*h[1] + h[2]*h[2] + h[3]*h[3] + h[4]*h[4]));
      #pragma unroll
      for (int m = 0; m < 5; m++){
        int r = m*64 + n;
        int byt = r*64 + ((v*2) ^ ((r&3)<<4));
        *(unsigned short*)((char*)Hs + byt) = f2bf(h[m]*g);
      }
    }
  }
  __syncthreads();
  const int lane = tid & 63, wv = tid >> 6;
  const int hi = lane >> 4, col = lane & 15;
  for (int mi = 0; mi < 5; mi++){
    int mt = wv*5 + mi;
    bf16x8 afr;
    {
      int row = mt*16 + (lane & 15);
      int byt = row*64 + ((hi*16) ^ ((row&3)<<4));
      afr = *(const bf16x8*)((const char*)Hs + byt);
    }
    int m = mt >> 2, nlb = (mt & 3)*16;
    for (int nt = 0; nt < 2; nt++){
      f32x4 acc = {0.f, 0.f, 0.f, 0.f};
      bf16x8 bfr = *(const bf16x8*)(b2 + ((long)nt*64 + lane)*8);
      acc = __builtin_amdgcn_mfma_f32_16x16x32_bf16(afr, bfr, acc, 0, 0, 0);
      int v = nt*16 + col;
      float ssl = 0.f;
      #pragma unroll
      for (int j = 0; j < 4; j++){
        int g = n0 + nlb + hi*4 + j;
        if (g < NN){
          stf<true>(out, (long)g*480 + 320 + v*5 + m, acc[j]);
          ssl += acc[j]*acc[j];
        }
      }
      atomicAdd(&ssL[v], ssl);
    }
  }
  __syncthreads();
  if (tid < 32) atomicAdd(&stats2[tid], ssL[tid]);
}

__global__ __launch_bounds__(256) void c_fused(const float* __restrict__ a,
    const void* __restrict__ tp, const void* __restrict__ w0a,
    const void* __restrict__ w1a, const void* __restrict__ w2a,
    const unsigned short* __restrict__ b0, const unsigned short* __restrict__ b1,
    const unsigned short* __restrict__ b2, const int* __restrict__ flag,
    void* __restrict__ out, float* __restrict__ stats,
    const float* __restrict__ w222)
{
  if (*flag == 0) return;  // f32 handled by fallback kernels
  __shared__ __align__(16) char smem[29056];
  const int b = blockIdx.x;
  if (b < NB_C)            c0_body(b,          a, tp, w0a, b0, out, stats,       smem);
  else if (b < 2*NB_C)     c1_body(b - NB_C,   a, tp, w1a, b1, out, stats + 256, smem);
  else                     c2_body(b - 2*NB_C, a, tp, w2a, b2, out, stats + 320, w222, smem);
}

// ===========================================================================
// f32 fallback c-kernels (insurance; early-exit on bf16 data)
// ===========================================================================
template<bool BF>
__global__ __launch_bounds__(256) void c0_kernel(const float* __restrict__ a,
    const void* __restrict__ tp, const void* __restrict__ w0a, const void* __restrict__ w0b,
    const int* __restrict__ flag, void* __restrict__ out, float* __restrict__ stats)
{
  if ((*flag != 0) != BF) return;
  __shared__ float W0aL[384];
  __shared__ float W0bL[16384];
  __shared__ float h0L[16*128];
  __shared__ float o0L[16*3];
  __shared__ float sumL[128], sqL[128];
  const int tid = threadIdx.x;
  const int c = tid & 127, half = tid >> 7;
  const int n0 = blockIdx.x * 16;
  for (int i = tid; i < 384; i += 256) W0aL[i] = ldf<BF>(w0a, i);
  for (int i = tid; i < 16384; i += 256) W0bL[i] = ldf<BF>(w0b, i);
  if (tid < 128){ sumL[tid] = 0.f; sqL[tid] = 0.f; }
  if (tid < 48){
    int n = tid / 3, j = tid - n*3;
    const float* an = a + (long)(n0 + n) * 9;
    float tpj = ldf<BF>(tp, j);
    float v;
    if (j == 0)      v = tpj * an[0]*an[0];
    else if (j == 1) v = tpj * (an[1]*an[1] + an[2]*an[2] + an[3]*an[3]) * INV_SQ3f;
    else             v = tpj * (an[4]*an[4] + an[5]*an[5] + an[6]*an[6] + an[7]*an[7] + an[8]*an[8]) * INV_SQ5f;
    o0L[tid] = v;
  }
  __syncthreads();
  #pragma unroll
  for (int i = 0; i < 8; i++){
    int n = half*8 + i;
    float pre = o0L[n*3]*W0aL[c] + o0L[n*3+1]*W0aL[128+c] + o0L[n*3+2]*W0aL[256+c];
    h0L[n*128 + c] = sigf(pre);
  }
  __syncthreads();
  float acc[8];
  #pragma unroll
  for (int i = 0; i < 8; i++) acc[i] = 0.f;
  for (int k = 0; k < 128; k++){
    float w = W0bL[k*128 + c];
    #pragma unroll
    for (int i = 0; i < 8; i++) acc[i] += h0L[(half*8 + i)*128 + k] * w;
  }
  float lsum = 0.f, lsq = 0.f;
  #pragma unroll
  for (int i = 0; i < 8; i++){
    int n = half*8 + i;
    stf<BF>(out, (long)(n0 + n)*480 + c, acc[i]);
    lsum += acc[i]; lsq += acc[i]*acc[i];
  }
  atomicAdd(&sumL[c], lsum); atomicAdd(&sqL[c], lsq);
  __syncthreads();
  if (tid < 128){ atomicAdd(&stats[tid], sumL[tid]); atomicAdd(&stats[128 + tid], sqL[tid]); }
}

template<bool BF>
__global__ __launch_bounds__(256) void c1_kernel(const float* __restrict__ a,
    const void* __restrict__ tp, const void* __restrict__ w1a, const void* __restrict__ w1b,
    const int* __restrict__ flag, void* __restrict__ out, float* __restrict__ stats1)
{
  if ((*flag != 0) != BF) return;
  __shared__ float W1aL[256];
  __shared__ float W1bL[4096];
  __shared__ float h1L[32*64*3];
  __shared__ float o1L[32*12];
  __shared__ float ssL[64];
  const int tid = threadIdx.x;
  const int v = tid & 63, ng = tid >> 6;
  const int n0 = blockIdx.x * 32;
  for (int i = tid; i < 256; i += 256) W1aL[i] = ldf<BF>(w1a, i);
  for (int i = tid; i < 4096; i += 256) W1bL[i] = ldf<BF>(w1b, i);
  if (tid < 64) ssL[tid] = 0.f;
  float tp3 = ldf<BF>(tp, 3), tp4 = ldf<BF>(tp, 4), tp5 = ldf<BF>(tp, 5), tp6 = ldf<BF>(tp, 6);
  for (int idx = tid; idx < 384; idx += 256){
    int n = idx / 12, r = idx - n*12;
    int u = r / 3, m = r - u*3;
    const float* an = a + (long)(n0 + n) * 9;
    float s1x = an[1], s1y = an[2], s1z = an[3];
    float val;
    if (u == 0)      val = tp3 * an[0] * an[1 + m];
    else if (u == 1) val = tp4 * an[1 + m] * an[0];
    else {
      float e1m;
      if (m == 0)      e1m = C_Hf*(an[4]*s1z + an[5]*s1y - an[8]*s1x) - C_S5Hf*an[6]*s1x;
      else if (m == 1) e1m = C_Hf*(an[5]*s1x + an[7]*s1z) + C_S5f*an[6]*s1y;
      else             e1m = C_Hf*(an[4]*s1x + an[7]*s1y + an[8]*s1z) - C_S5Hf*an[6]*s1z;
      val = (u == 2 ? tp5 : tp6) * e1m;
    }
    o1L[idx] = val;
  }
  __syncthreads();
  #pragma unroll
  for (int i = 0; i < 8; i++){
    int n = ng*8 + i;
    float h[3];
    #pragma unroll
    for (int m = 0; m < 3; m++){
      float s = 0.f;
      #pragma unroll
      for (int u = 0; u < 4; u++) s += o1L[n*12 + u*3 + m] * W1aL[u*64 + v];
      h[m] = s;
    }
    float g = sigf(sqrtf(h[0]*h[0] + h[1]*h[1] + h[2]*h[2]));
    int b = (n*64 + v)*3;
    h1L[b] = h[0]*g; h1L[b+1] = h[1]*g; h1L[b+2] = h[2]*g;
  }
  __syncthreads();
  float ss = 0.f;
  for (int i = 0; i < 8; i++){
    int n = ng*8 + i;
    float a0 = 0.f, a1 = 0.f, a2 = 0.f;
    for (int u = 0; u < 64; u++){
      float w = W1bL[u*64 + v];
      const float* hp = &h1L[(n*64 + u)*3];
      a0 += hp[0]*w; a1 += hp[1]*w; a2 += hp[2]*w;
    }
    long b = (long)(n0 + n)*480 + 128 + v*3;
    stf<BF>(out, b, a0); stf<BF>(out, b+1, a1); stf<BF>(out, b+2, a2);
    ss += a0*a0 + a1*a1 + a2*a2;
  }
  atomicAdd(&ssL[v], ss);
  __syncthreads();
  if (tid < 64) atomicAdd(&stats1[tid], ssL[tid]);
}

template<bool BF>
__global__ __launch_bounds__(256) void c2_kernel(const float* __restrict__ a,
    const void* __restrict__ tp, const void* __restrict__ w2a, const void* __restrict__ w2b,
    const int* __restrict__ flag, void* __restrict__ out, float* __restrict__ stats2,
    const float* __restrict__ w222)
{
  if ((*flag != 0) != BF) return;
  __shared__ float W2aL[128];
  __shared__ float W2bL[1024];
  __shared__ float h2L[32*32*5];
  __shared__ float o2L[32*20];
  __shared__ float ssL[32];
  const int tid = threadIdx.x;
  const int v = tid & 31, ng = tid >> 5;
  const int n0 = blockIdx.x * 32;
  for (int i = tid; i < 128; i += 256) W2aL[i] = ldf<BF>(w2a, i);
  for (int i = tid; i < 1024; i += 256) W2bL[i] = ldf<BF>(w2b, i);
  if (tid < 32) ssL[tid] = 0.f;
  float tp7 = ldf<BF>(tp, 7), tp8 = ldf<BF>(tp, 8), tp9 = ldf<BF>(tp, 9), tp10 = ldf<BF>(tp, 10);
  for (int idx = tid; idx < 640; idx += 256){
    int n = idx / 20, r = idx - n*20, u = r / 5, m = r - u*5;
    const float* an = a + (long)(n0 + n) * 9;
    float x1 = an[1], y1 = an[2], z1 = an[3];
    float val;
    if (u == 0)      val = tp7 * an[0] * an[4 + m];
    else if (u == 1) val = tp8 * an[4 + m] * an[0];
    else if (u == 2){
      float pm;
      if (m == 0)      pm = 2.f*C_Hf*x1*z1;
      else if (m == 1) pm = 2.f*C_Hf*x1*y1;
      else if (m == 2) pm = C_S5f*y1*y1 - C_S5Hf*(x1*x1 + z1*z1);
      else if (m == 3) pm = 2.f*C_Hf*y1*z1;
      else             pm = C_Hf*(z1*z1 - x1*x1);
      val = tp9 * pm;
    } else {
      float q = 0.f;
      #pragma unroll
      for (int aa = 0; aa < 5; aa++){
        float sa = an[4 + aa];
        #pragma unroll
        for (int bb = 0; bb < 5; bb++) q += w222[aa*25 + bb*5 + m] * sa * an[4 + bb];
      }
      val = tp10 * q;
    }
    o2L[idx] = val;
  }
  __syncthreads();
  #pragma unroll
  for (int i = 0; i < 4; i++){
    int n = ng*4 + i;
    float h[5];
    #pragma unroll
    for (int m = 0; m < 5; m++){
      float s = 0.f;
      #pragma unroll
      for (int u = 0; u < 4; u++) s += o2L[n*20 + u*5 + m] * W2aL[u*32 + v];
      h[m] = s;
    }
    float g = sigf(sqrtf(h[0]*h[0] + h[1]*h[1] + h[2]*h[2] + h[3]*h[3] + h[4]*h[4]));
    int b = (n*32 + v)*5;
    #pragma unroll
    for (int m = 0; m < 5; m++) h2L[b + m] = h[m]*g;
  }
  __syncthreads();
  float ss = 0.f;
  #pragma unroll
  for (int i = 0; i < 4; i++){
    int n = ng*4 + i;
    float acc[5] = {0.f, 0.f, 0.f, 0.f, 0.f};
    for (int u = 0; u < 32; u++){
      float w = W2bL[u*32 + v];
      const float* hp = &h2L[(n*32 + u)*5];
      #pragma unroll
      for (int m = 0; m < 5; m++) acc[m] += hp[m]*w;
    }
    long b = (long)(n0 + n)*480 + 320 + v*5;
    #pragma unroll
    for (int m = 0; m < 5; m++) stf<BF>(out, b + m, acc[m]);
    #pragma unroll
    for (int m = 0; m < 5; m++) ss += acc[m]*acc[m];
  }
  atomicAdd(&ssL[v], ss);
  __syncthreads();
  if (tid < 32) atomicAdd(&stats2[tid], ssL[tid]);
}

// ---------------------------------------------------------------------------
// finalize: per-channel scale/bias table (480 each) for the fused norm pass.
// ---------------------------------------------------------------------------
__global__ void finalize_kernel(const float* __restrict__ stats, float* __restrict__ params){
  int t = threadIdx.x;
  if (t >= 480) return;
  float sc, bi = 0.f;
  if (t < 128){
    float mean = stats[t] * (1.0f/NN);
    float var  = stats[128 + t] * (1.0f/NN) - mean*mean;
    sc = 1.0f / sqrtf(fmaxf(var, 0.f) + EPSf);
    bi = -mean * sc;
  } else if (t < 320){
    int v = (t - 128) / 3;
    sc = 1.0f / sqrtf(stats[256 + v] * (1.0f/(NN*3.0f)) + EPSf);
  } else {
    int v = (t - 320) / 5;
    sc = 1.0f / sqrtf(stats[320 + v] * (1.0f/(NN*5.0f)) + EPSf);
  }
  params[t] = sc;
  params[480 + t] = bi;
}

// ---------------------------------------------------------------------------
// norm: one grid-stride kernel, both dtypes. Per 4-byte word (2 bf16 or
// half a float2-pair): j = (idx%240)*2; r = v*scale[j] + bias[j].
// ---------------------------------------------------------------------------
__global__ __launch_bounds__(256) void norm_kernel(const int* __restrict__ flag,
    void* __restrict__ out, const float* __restrict__ params)
{
  __shared__ float scL[480], biL[480];
  const int tid = threadIdx.x;
  for (int i = tid; i < 480; i += 256){ scL[i] = params[i]; biL[i] = params[480 + i]; }
  __syncthreads();
  const bool bf = (*flag != 0);
  const long TOT = (long)NN * 240;
  const long stride = (long)gridDim.x * 256;
  for (long idx = (long)blockIdx.x * 256 + tid; idx < TOT; idx += stride){
    int t240 = (int)(idx % 240);
    int j = t240 * 2;
    if (bf){
      unsigned int w = ((const unsigned int*)out)[idx];
      float v0 = bf2f((unsigned short)(w & 0xffffu));
      float v1 = bf2f((unsigned short)(w >> 16));
      float r0 = v0 * scL[j]   + biL[j];
      float r1 = v1 * scL[j+1] + biL[j+1];
      ((unsigned int*)out)[idx] = (unsigned)f2bf(r0) | ((unsigned)f2bf(r1) << 16);
    } else {
      float2 w = ((const float2*)out)[idx];
      float r0 = w.x * scL[j]   + biL[j];
      float r1 = w.y * scL[j+1] + biL[j+1];
      ((float2*)out)[idx] = make_float2(r0, r1);
    }
  }
}

// ---------------------------------------------------------------------------
extern "C" void kernel_launch(void* const* d_in, const int* in_sizes, int n_in,
                              void* d_out, int out_size, void* d_ws, size_t ws_size,
                              hipStream_t stream) {
  const void* x   = d_in[0];
  const void* pos = d_in[1];
  const int*  ei  = (const int*)d_in[2];
  const void* tp  = d_in[3];
  const void* w0a = d_in[4];
  const void* w1a = d_in[5];
  const void* w2a = d_in[6];
  const void* w0b = d_in[7];
  const void* w1b = d_in[8];
  const void* w2b = d_in[9];

  // ws layout: [0,4) flag | [64, 400064) cnt (NN int) | [400064, 4000064) a (NN*9 f32)
  //          | [4000064,...) stats(352) | params(960) | w222(125) | bfrag packs
  int*   flag   = (int*)d_ws;
  int*   cnt    = (int*)((char*)d_ws + 64);
  float* a      = (float*)((char*)d_ws + 400064);
  float* stats  = (float*)((char*)d_ws + 4000064);
  float* params = stats + 352;
  float* w222   = params + 960;
  unsigned short* b0 = (unsigned short*)((char*)d_ws + 4006016);
  unsigned short* b1 = b0 + 16384;
  unsigned short* b2 = b1 + 4096;

  // CSR scratch lives in d_out's node region (32MB < node region), overwritten later.
  int* csr = (int*)d_out;

  hipMemsetAsync(d_ws, 0, 4001472, stream);
  setup_kernel<<<1, 256, 0, stream>>>(x, flag, w222, w0b, w1b, w2b, b0, b1, b2);

  edge_kernel<<<NE/256, 256, 0, stream>>>(x, pos, ei, flag, cnt, csr, a, d_out);
  agg_kernel <<<NN/4,   256, 0, stream>>>(x, pos, flag, cnt, csr, a);

  // bf16 path: fused MFMA kernel (c0 | c1 | c2 by block range)
  c_fused<<<3*NB_C, 256, 0, stream>>>(a, tp, w0a, w1a, w2a, b0, b1, b2, flag,
                                      d_out, stats, w222);

  // f32 fallback path (early-exits when bf16)
  c0_kernel<false><<<NN/16, 256, 0, stream>>>(a, tp, w0a, w0b, flag, d_out, stats);
  c1_kernel<false><<<NN/32, 256, 0, stream>>>(a, tp, w1a, w1b, flag, d_out, stats + 256);
  c2_kernel<false><<<NN/32, 256, 0, stream>>>(a, tp, w2a, w2b, flag, d_out, stats + 320, w222);

  finalize_kernel<<<1, 512, 0, stream>>>(stats, params);

  norm_kernel<<<2048, 256, 0, stream>>>(flag, d_out, params);
}

// Round 4
// 1276.893 us; speedup vs baseline: 1.0607x; 1.0063x over previous
//
#include <hip/hip_runtime.h>
#include <math.h>

#define NN 100000
#define NE 3200000
#define CAP 80   /* CSR slots per node; Poisson(32) => P(any node >80) ~ 1e-7; overflow falls back to atomics */

#define SQ3f   1.7320508075688772f
#define SQ5f   2.2360679774997896f
#define SQ15f  3.8729833462074170f
#define INV_SQ3f 0.57735026918962576f
#define INV_SQ5f 0.44721359549995794f
#define C_Hf   0.31622776601683794f   /* sqrt(15)/2 / sqrt(37.5) */
#define C_S5f  0.36514837167011072f   /* sqrt(5)   / sqrt(37.5) */
#define C_S5Hf 0.18257418583505536f   /* sqrt(5)/2 / sqrt(37.5) */
#define ERBF_K 0.44721359549995794f   /* sqrt(2/10) */
#define PI_OVER_CUT 0.31415926535897931f
#define INV_CUT 0.1f
#define EPSf 1e-5f

#define ERBF_OFF 48000000L   /* NN*480 */
#define ERSH_OFF 99200000L   /* +NE*16 */

#define NB_C 1563            /* blocks per c-section: 64 nodes/block */

typedef __attribute__((ext_vector_type(8))) short bf16x8;
typedef __attribute__((ext_vector_type(4))) float f32x4;

__device__ __forceinline__ float bf2f(unsigned short b){
  union { unsigned int u; float f; } c; c.u = ((unsigned int)b) << 16; return c.f;
}
__device__ __forceinline__ unsigned short f2bf(float f){
  union { float f; unsigned int u; } c; c.f = f;
  unsigned int u = c.u;
  return (unsigned short)((u + 0x7fffu + ((u >> 16) & 1u)) >> 16);
}
template<bool BF> __device__ __forceinline__ float ldf(const void* p, long i){
  if (BF) return bf2f(((const unsigned short*)p)[i]);
  return ((const float*)p)[i];
}
template<bool BF> __device__ __forceinline__ void stf(void* p, long i, float v){
  if (BF) ((unsigned short*)p)[i] = f2bf(v);
  else ((float*)p)[i] = v;
}
__device__ __forceinline__ float sigf(float v){ return 1.0f / (1.0f + expf(-v)); }

// vectorized gathers
template<bool BF> __device__ __forceinline__ void ld_pos3(const void* pos, long idx, float r[3]){
  if (BF){
    const unsigned short* p = (const unsigned short*)pos + idx*3;
    unsigned int w; __builtin_memcpy(&w, p, 4);
    r[0] = bf2f((unsigned short)(w & 0xffffu));
    r[1] = bf2f((unsigned short)(w >> 16));
    r[2] = bf2f(p[2]);
  } else {
    const float* p = (const float*)pos + idx*3;
    float2 v; __builtin_memcpy(&v, p, 8);
    r[0] = v.x; r[1] = v.y; r[2] = p[2];
  }
}
template<bool BF> __device__ __forceinline__ void ld_x9(const void* x, long row, float o[9]){
  if (BF){
    const unsigned short* p = (const unsigned short*)x + row*9;
    uint4 w; __builtin_memcpy(&w, p, 16);
    o[0]=bf2f((unsigned short)(w.x & 0xffffu)); o[1]=bf2f((unsigned short)(w.x >> 16));
    o[2]=bf2f((unsigned short)(w.y & 0xffffu)); o[3]=bf2f((unsigned short)(w.y >> 16));
    o[4]=bf2f((unsigned short)(w.z & 0xffffu)); o[5]=bf2f((unsigned short)(w.z >> 16));
    o[6]=bf2f((unsigned short)(w.w & 0xffffu)); o[7]=bf2f((unsigned short)(w.w >> 16));
    o[8]=bf2f(p[8]);
  } else {
    const float* p = (const float*)x + row*9;
    float4 A, B; __builtin_memcpy(&A, p, 16); __builtin_memcpy(&B, p + 4, 16);
    o[0]=A.x; o[1]=A.y; o[2]=A.z; o[3]=A.w;
    o[4]=B.x; o[5]=B.y; o[6]=B.z; o[7]=B.w;
    o[8]=p[8];
  }
}

__device__ __forceinline__ void edge_geom(float vx, float vy, float vz,
    float& ux, float& uy, float& uz, float sh[5],
    float& g0, float& g1, float& g2, float& dist, float& rinv, float& fc)
{
  dist = sqrtf(vx*vx + vy*vy + vz*vz);
  rinv = 1.0f / fmaxf(dist, 1e-12f);
  ux = vx*rinv; uy = vy*rinv; uz = vz*rinv;
  sh[0] = SQ15f*ux*uz;
  sh[1] = SQ15f*ux*uy;
  sh[2] = SQ5f*(uy*uy - 0.5f*(ux*ux + uz*uz));
  sh[3] = SQ15f*uy*uz;
  sh[4] = 0.5f*SQ15f*(uz*uz - ux*ux);
  float d = dist * INV_CUT;
  float d2 = d*d, d5 = d2*d2*d;
  fc = 1.0f - 21.0f*d5 + 35.0f*d5*d - 15.0f*d5*d2;
  fc = (d < 1.0f) ? fc : 0.0f;
  float eg = expf(-d2);
  g0 = eg*fc; g1 = g0*d; g2 = g1*d;
}

// ---------------------------------------------------------------------------
// setup: dtype flag + W222 (thread 0) ; then pack MFMA B-fragments (all threads)
// ---------------------------------------------------------------------------
__global__ void setup_kernel(const void* __restrict__ x, int* __restrict__ flag,
                             float* __restrict__ w222,
                             const void* __restrict__ w0b, const void* __restrict__ w1b,
                             const void* __restrict__ w2b,
                             unsigned short* __restrict__ b0, unsigned short* __restrict__ b1,
                             unsigned short* __restrict__ b2){
  __shared__ int shf;
  const int tid = threadIdx.x;
  if (tid == 0){
    int isbf = 1;
    const unsigned short* p = (const unsigned short*)x;
    for (int i = 0; i < 256; i++){
      float v = bf2f(p[i]);
      if (!(fabsf(v) < 1e4f)) { isbf = 0; break; }
    }
    *flag = isbf;
    shf = isbf;

    double A[5][3][3];
    for (int m = 0; m < 5; m++) for (int i = 0; i < 3; i++) for (int j = 0; j < 3; j++) A[m][i][j] = 0.0;
    const double h = 1.9364916731037085;  // sqrt(15)/2
    const double s5 = 2.2360679774997896; // sqrt(5)
    A[0][0][2] = h;  A[0][2][0] = h;
    A[1][0][1] = h;  A[1][1][0] = h;
    A[2][0][0] = -0.5*s5; A[2][1][1] = s5; A[2][2][2] = -0.5*s5;
    A[3][1][2] = h;  A[3][2][1] = h;
    A[4][0][0] = -h; A[4][2][2] = h;
    double W[125];
    for (int m = 0; m < 5; m++) for (int n = 0; n < 5; n++) for (int q = 0; q < 5; q++){
      double s = 0.0;
      for (int i = 0; i < 3; i++) for (int k = 0; k < 3; k++) for (int j = 0; j < 3; j++)
        s += A[m][i][k] * A[n][k][j] * A[q][j][i];
      W[m*25 + n*5 + q] = s;
    }
    double nrm2 = 0.0;
    double W2[125];
    for (int m = 0; m < 5; m++) for (int n = 0; n < 5; n++) for (int q = 0; q < 5; q++){
      double s = W[m*25 + n*5 + q] + W[n*25 + m*5 + q];
      W2[m*25 + n*5 + q] = s;
      nrm2 += s * s;
    }
    double inv = 1.0 / sqrt(nrm2);
    for (int i = 0; i < 125; i++) w222[i] = (float)(W2[i] * inv);
  }
  __syncthreads();
  if (shf == 0) return;   // f32 path never uses MFMA fragments
  const unsigned short* s0 = (const unsigned short*)w0b;
  for (int i = tid; i < 16384; i += 256){
    int j = i & 7, lane = (i>>3)&63, nt = (i>>9)&7, ks = i>>12;
    int k = ks*32 + (lane>>4)*8 + j, c = nt*16 + (lane&15);
    b0[i] = s0[k*128 + c];
  }
  const unsigned short* s1 = (const unsigned short*)w1b;
  for (int i = tid; i < 4096; i += 256){
    int j = i & 7, lane = (i>>3)&63, nt = (i>>9)&3, ks = i>>11;
    int k = ks*32 + (lane>>4)*8 + j, c = nt*16 + (lane&15);
    b1[i] = s1[k*64 + c];
  }
  const unsigned short* s2 = (const unsigned short*)w2b;
  for (int i = tid; i < 1024; i += 256){
    int j = i & 7, lane = (i>>3)&63, nt = (i>>9)&1;
    int k = (lane>>4)*8 + j, c = nt*16 + (lane&15);
    b2[i] = s2[k*32 + c];
  }
}

// ---------------------------------------------------------------------------
// Edge: build CSR (1 int atomic/edge), write erbf (vectorized) and ersh
// (LDS-staged -> coalesced u32). Single launch, uniform branch on dtype.
// ---------------------------------------------------------------------------
template<bool BF>
__device__ __forceinline__ void edge_body(
    const void* __restrict__ x, const void* __restrict__ pos, const int* __restrict__ ei,
    int* __restrict__ cnt, int* __restrict__ csr,
    float* __restrict__ a, void* __restrict__ out, char* ershS)
{
  const int tid = threadIdx.x;
  const int e = blockIdx.x * 256 + tid;
  const int src = ei[e], dst = ei[NE + e];
  float sp[3], dp[3];
  ld_pos3<BF>(pos, src, sp);
  ld_pos3<BF>(pos, dst, dp);
  // permutation: new (x,y,z) = (pos1, pos2, pos0)
  float vx = dp[1]-sp[1], vy = dp[2]-sp[2], vz = dp[0]-sp[0];
  float ux, uy, uz, sh[5], g0, g1, g2, dist, rinv, fc;
  edge_geom(vx, vy, vz, ux, uy, uz, sh, g0, g1, g2, dist, rinv, fc);

  int slot = atomicAdd(&cnt[dst], 1);
  if (slot < CAP){
    csr[(long)dst*CAP + slot] = src;
  } else {
    float xr[9]; ld_x9<BF>(x, src, xr);
    float* ad = a + (long)dst * 9;
    atomicAdd(ad + 0, xr[0] * g0);
    atomicAdd(ad + 1, xr[1] * (SQ3f*ux) * g1);
    atomicAdd(ad + 2, xr[2] * (SQ3f*uy) * g1);
    atomicAdd(ad + 3, xr[3] * (SQ3f*uz) * g1);
    atomicAdd(ad + 4, xr[4] * sh[0] * g2);
    atomicAdd(ad + 5, xr[5] * sh[1] * g2);
    atomicAdd(ad + 6, xr[6] * sh[2] * g2);
    atomicAdd(ad + 7, xr[7] * sh[3] * g2);
    atomicAdd(ad + 8, xr[8] * sh[4] * g2);
  }

  // erbf via Chebyshev recurrence
  float t = PI_OVER_CUT * dist;
  float st = sinf(t), c2t = 2.0f*cosf(t);
  float kk = ERBF_K * fc * rinv;
  float snm1 = 0.0f, sn = st;
  if (BF){
    unsigned short eb[16];
    #pragma unroll
    for (int n = 0; n < 16; n++){
      eb[n] = f2bf(sn * kk);
      float nx = c2t*sn - snm1; snm1 = sn; sn = nx;
    }
    uint4* q = (uint4*)((unsigned short*)out + ERBF_OFF + (long)e*16);
    q[0] = make_uint4((unsigned)eb[0] | ((unsigned)eb[1] << 16),
                      (unsigned)eb[2] | ((unsigned)eb[3] << 16),
                      (unsigned)eb[4] | ((unsigned)eb[5] << 16),
                      (unsigned)eb[6] | ((unsigned)eb[7] << 16));
    q[1] = make_uint4((unsigned)eb[8]  | ((unsigned)eb[9]  << 16),
                      (unsigned)eb[10] | ((unsigned)eb[11] << 16),
                      (unsigned)eb[12] | ((unsigned)eb[13] << 16),
                      (unsigned)eb[14] | ((unsigned)eb[15] << 16));
  } else {
    float er[16];
    #pragma unroll
    for (int n = 0; n < 16; n++){
      er[n] = sn * kk;
      float nx = c2t*sn - snm1; snm1 = sn; sn = nx;
    }
    float4* q = (float4*)((float*)out + ERBF_OFF + (long)e*16);
    q[0] = make_float4(er[0], er[1], er[2], er[3]);
    q[1] = make_float4(er[4], er[5], er[6], er[7]);
    q[2] = make_float4(er[8], er[9], er[10], er[11]);
    q[3] = make_float4(er[12], er[13], er[14], er[15]);
  }
  // ersh = sph_l012(-vec): stage tile in LDS, then coalesced u32 copy-out
  if (BF){
    unsigned short* eL = (unsigned short*)ershS;
    unsigned short* m = eL + tid*9;
    m[0] = f2bf(1.0f);
    m[1] = f2bf(-SQ3f*ux); m[2] = f2bf(-SQ3f*uy); m[3] = f2bf(-SQ3f*uz);
    m[4] = f2bf(sh[0]); m[5] = f2bf(sh[1]); m[6] = f2bf(sh[2]);
    m[7] = f2bf(sh[3]); m[8] = f2bf(sh[4]);
  } else {
    float* eL = (float*)ershS;
    float* m = eL + tid*9;
    m[0] = 1.0f;
    m[1] = -SQ3f*ux; m[2] = -SQ3f*uy; m[3] = -SQ3f*uz;
    m[4] = sh[0]; m[5] = sh[1]; m[6] = sh[2]; m[7] = sh[3]; m[8] = sh[4];
  }
  __syncthreads();
  const unsigned int* srcw = (const unsigned int*)ershS;
  if (BF){
    unsigned int* dstw = (unsigned int*)((unsigned short*)out + ERSH_OFF + (long)blockIdx.x*256*9);
    #pragma unroll
    for (int w = 0; w < 5; w++){
      int i = w*256 + tid;
      if (i < 1152) dstw[i] = srcw[i];
    }
  } else {
    unsigned int* dstw = (unsigned int*)((float*)out + ERSH_OFF + (long)blockIdx.x*256*9);
    #pragma unroll
    for (int w = 0; w < 9; w++){
      int i = w*256 + tid;
      if (i < 2304) dstw[i] = srcw[i];
    }
  }
}

__global__ __launch_bounds__(256) void edge_kernel(
    const void* __restrict__ x, const void* __restrict__ pos, const int* __restrict__ ei,
    const int* __restrict__ flag, int* __restrict__ cnt, int* __restrict__ csr,
    float* __restrict__ a, void* __restrict__ out)
{
  __shared__ __align__(16) char ershS[256*9*4];
  if (*flag) edge_body<true >(x, pos, ei, cnt, csr, a, out, ershS);
  else       edge_body<false>(x, pos, ei, cnt, csr, a, out, ershS);
}

// ---------------------------------------------------------------------------
// Aggregation: 32 lanes per node (mean degree 32 -> full lane utilization),
// 8 nodes per 256-block; gather+recompute+shuffle-reduce; zero atomics.
// ---------------------------------------------------------------------------
template<bool BF>
__device__ __forceinline__ void agg_body(
    const void* __restrict__ x, const void* __restrict__ pos,
    const int* __restrict__ cnt, const int* __restrict__ csr,
    float* __restrict__ a)
{
  const int tid = threadIdx.x;
  const int n = blockIdx.x * 8 + (tid >> 5);
  const int lane = tid & 31;
  float dp[3]; ld_pos3<BF>(pos, n, dp);
  int cn = cnt[n];
  int cc = cn < CAP ? cn : CAP;
  float acc[9];
  #pragma unroll
  for (int j = 0; j < 9; j++) acc[j] = 0.f;
  for (int slot = lane; slot < cc; slot += 32){
    int src = csr[(long)n*CAP + slot];
    float sp[3]; ld_pos3<BF>(pos, src, sp);
    float xr[9]; ld_x9<BF>(x, src, xr);
    float vx = dp[1]-sp[1], vy = dp[2]-sp[2], vz = dp[0]-sp[0];
    float ux, uy, uz, sh[5], g0, g1, g2, dist, rinv, fc;
    edge_geom(vx, vy, vz, ux, uy, uz, sh, g0, g1, g2, dist, rinv, fc);
    acc[0] += xr[0] * g0;
    acc[1] += xr[1] * (SQ3f*ux) * g1;
    acc[2] += xr[2] * (SQ3f*uy) * g1;
    acc[3] += xr[3] * (SQ3f*uz) * g1;
    acc[4] += xr[4] * sh[0] * g2;
    acc[5] += xr[5] * sh[1] * g2;
    acc[6] += xr[6] * sh[2] * g2;
    acc[7] += xr[7] * sh[3] * g2;
    acc[8] += xr[8] * sh[4] * g2;
  }
  // reduce within the 32-lane group (xor masks <32 stay inside the group)
  #pragma unroll
  for (int j = 0; j < 9; j++){
    #pragma unroll
    for (int off = 16; off > 0; off >>= 1)
      acc[j] += __shfl_xor(acc[j], off, 64);
  }
  if (lane == 0){
    float* an = a + (long)n * 9;
    #pragma unroll
    for (int j = 0; j < 9; j++) an[j] += acc[j];
  }
}

__global__ __launch_bounds__(256) void agg_kernel(
    const void* __restrict__ x, const void* __restrict__ pos,
    const int* __restrict__ flag, const int* __restrict__ cnt,
    const int* __restrict__ csr, float* __restrict__ a)
{
  if (*flag) agg_body<true >(x, pos, cnt, csr, a);
  else       agg_body<false>(x, pos, cnt, csr, a);
}

// ===========================================================================
// Fused MFMA c-kernel (bf16 path). One launch: blocks [0,NB_C)=c0,
// [NB_C,2NB_C)=c1, [2NB_C,3NB_C)=c2. Shared memory carved from one pool.
// mfma_f32_16x16x32_bf16: A row=lane&15,k=(lane>>4)*8+j; B col=lane&15,same k;
// C col=lane&15,row=(lane>>4)*4+j.  LDS swizzle: byte ^= (row&7)<<4.
// ===========================================================================
__device__ void c0_body(int bid, const float* __restrict__ a,
    const void* __restrict__ tp, const void* __restrict__ w0a,
    const unsigned short* __restrict__ b0,
    void* __restrict__ out, float* __restrict__ stats, char* smem)
{
  float* W0aL = (float*)smem;               // 384 f
  float* o0L  = (float*)(smem + 1536);      // 192 f
  float* sumL = (float*)(smem + 2304);      // 128 f
  float* sqL  = (float*)(smem + 2816);      // 128 f
  unsigned short* Hs = (unsigned short*)(smem + 3328);  // 64*128 bf16, rows 256B
  const int tid = threadIdx.x;
  const int n0 = bid * 64;
  for (int i = tid; i < 384; i += 256) W0aL[i] = ldf<true>(w0a, i);
  if (tid < 128){ sumL[tid] = 0.f; sqL[tid] = 0.f; }
  if (tid < 192){
    int n = tid / 3, j = tid - n*3;
    float v = 0.f;
    if (n0 + n < NN){
      const float* an = a + (long)(n0 + n) * 9;
      float tpj = ldf<true>(tp, j);
      if (j == 0)      v = tpj * an[0]*an[0];
      else if (j == 1) v = tpj * (an[1]*an[1] + an[2]*an[2] + an[3]*an[3]) * INV_SQ3f;
      else             v = tpj * (an[4]*an[4] + an[5]*an[5] + an[6]*an[6] + an[7]*an[7] + an[8]*an[8]) * INV_SQ5f;
    }
    o0L[tid] = v;
  }
  __syncthreads();
  {
    const int cp = tid & 63, nb = tid >> 6;
    #pragma unroll
    for (int it = 0; it < 16; it++){
      int n = it*4 + nb;
      float q0 = o0L[n*3], q1 = o0L[n*3+1], q2 = o0L[n*3+2];
      int c = cp*2;
      float p0 = q0*W0aL[c]   + q1*W0aL[128+c]   + q2*W0aL[256+c];
      float p1 = q0*W0aL[c+1] + q1*W0aL[128+c+1] + q2*W0aL[256+c+1];
      unsigned int pk = (unsigned)f2bf(sigf(p0)) | ((unsigned)f2bf(sigf(p1)) << 16);
      int byt = n*256 + ((c*2) ^ ((n&7)<<4));
      *(unsigned int*)((char*)Hs + byt) = pk;
    }
  }
  __syncthreads();
  const int lane = tid & 63, wv = tid >> 6;
  const int hi = lane >> 4, col = lane & 15;
  bf16x8 afr[4];
  #pragma unroll
  for (int ks = 0; ks < 4; ks++){
    int row = wv*16 + (lane & 15);
    int byt = row*256 + ((ks*64 + hi*16) ^ ((row&7)<<4));
    afr[ks] = *(const bf16x8*)((const char*)Hs + byt);
  }
  for (int nt = 0; nt < 8; nt++){
    f32x4 acc = {0.f, 0.f, 0.f, 0.f};
    #pragma unroll
    for (int ks = 0; ks < 4; ks++){
      bf16x8 bfr = *(const bf16x8*)(b0 + ((long)(ks*8 + nt)*64 + lane)*8);
      acc = __builtin_amdgcn_mfma_f32_16x16x32_bf16(afr[ks], bfr, acc, 0, 0, 0);
    }
    int ch = nt*16 + col;
    float s = 0.f, sq = 0.f;
    #pragma unroll
    for (int j = 0; j < 4; j++){
      int g = n0 + wv*16 + hi*4 + j;
      if (g < NN){
        stf<true>(out, (long)g*480 + ch, acc[j]);
        s += acc[j]; sq += acc[j]*acc[j];
      }
    }
    atomicAdd(&sumL[ch], s);
    atomicAdd(&sqL[ch], sq);
  }
  __syncthreads();
  if (tid < 128){ atomicAdd(&stats[tid], sumL[tid]); atomicAdd(&stats[128 + tid], sqL[tid]); }
}

__device__ void c1_body(int bid, const float* __restrict__ a,
    const void* __restrict__ tp, const void* __restrict__ w1a,
    const unsigned short* __restrict__ b1,
    void* __restrict__ out, float* __restrict__ stats1, char* smem)
{
  float* W1aL = (float*)smem;               // 256 f
  float* o1L  = (float*)(smem + 1024);      // 768 f
  float* ssL  = (float*)(smem + 4096);      // 64 f
  unsigned short* Hs = (unsigned short*)(smem + 4352);  // 192*64 bf16, rows 128B
  const int tid = threadIdx.x;
  const int n0 = bid * 64;
  for (int i = tid; i < 256; i += 256) W1aL[i] = ldf<true>(w1a, i);
  if (tid < 64) ssL[tid] = 0.f;
  float tp3 = ldf<true>(tp, 3), tp4 = ldf<true>(tp, 4), tp5 = ldf<true>(tp, 5), tp6 = ldf<true>(tp, 6);
  for (int idx = tid; idx < 768; idx += 256){
    int n = idx / 12, r = idx - n*12;
    int u = r / 3, m = r - u*3;
    float val = 0.f;
    if (n0 + n < NN){
      const float* an = a + (long)(n0 + n) * 9;
      float s1x = an[1], s1y = an[2], s1z = an[3];
      if (u == 0)      val = tp3 * an[0] * an[1 + m];
      else if (u == 1) val = tp4 * an[1 + m] * an[0];
      else {
        float e1m;
        if (m == 0)      e1m = C_Hf*(an[4]*s1z + an[5]*s1y - an[8]*s1x) - C_S5Hf*an[6]*s1x;
        else if (m == 1) e1m = C_Hf*(an[5]*s1x + an[7]*s1z) + C_S5f*an[6]*s1y;
        else             e1m = C_Hf*(an[4]*s1x + an[7]*s1y + an[8]*s1z) - C_S5Hf*an[6]*s1z;
        val = (u == 2 ? tp5 : tp6) * e1m;
      }
    }
    o1L[idx] = val;
  }
  __syncthreads();
  {
    const int v = tid & 63, nb = tid >> 6;
    #pragma unroll
    for (int it = 0; it < 16; it++){
      int n = it*4 + nb;
      float h0 = 0.f, h1 = 0.f, h2 = 0.f;
      #pragma unroll
      for (int u = 0; u < 4; u++){
        float w = W1aL[u*64 + v];
        h0 += o1L[n*12 + u*3 + 0]*w;
        h1 += o1L[n*12 + u*3 + 1]*w;
        h2 += o1L[n*12 + u*3 + 2]*w;
      }
      float g = sigf(sqrtf(h0*h0 + h1*h1 + h2*h2));
      unsigned short e0 = f2bf(h0*g), e1 = f2bf(h1*g), e2 = f2bf(h2*g);
      int r0 = n,       b0y = r0*128 + ((v*2) ^ ((r0&7)<<4));
      int r1 = 64 + n,  b1y = r1*128 + ((v*2) ^ ((r1&7)<<4));
      int r2 = 128 + n, b2y = r2*128 + ((v*2) ^ ((r2&7)<<4));
      *(unsigned short*)((char*)Hs + b0y) = e0;
      *(unsigned short*)((char*)Hs + b1y) = e1;
      *(unsigned short*)((char*)Hs + b2y) = e2;
    }
  }
  __syncthreads();
  const int lane = tid & 63, wv = tid >> 6;
  const int hi = lane >> 4, col = lane & 15;
  for (int mi = 0; mi < 3; mi++){
    int mt = wv*3 + mi;
    bf16x8 afr[2];
    #pragma unroll
    for (int ks = 0; ks < 2; ks++){
      int row = mt*16 + (lane & 15);
      int byt = row*128 + ((ks*64 + hi*16) ^ ((row&7)<<4));
      afr[ks] = *(const bf16x8*)((const char*)Hs + byt);
    }
    int m = mt >> 2, nlb = (mt & 3)*16;
    for (int nt = 0; nt < 4; nt++){
      f32x4 acc = {0.f, 0.f, 0.f, 0.f};
      #pragma unroll
      for (int ks = 0; ks < 2; ks++){
        bf16x8 bfr = *(const bf16x8*)(b1 + ((long)(ks*4 + nt)*64 + lane)*8);
        acc = __builtin_amdgcn_mfma_f32_16x16x32_bf16(afr[ks], bfr, acc, 0, 0, 0);
      }
      int v = nt*16 + col;
      float ssl = 0.f;
      #pragma unroll
      for (int j = 0; j < 4; j++){
        int g = n0 + nlb + hi*4 + j;
        if (g < NN){
          stf<true>(out, (long)g*480 + 128 + v*3 + m, acc[j]);
          ssl += acc[j]*acc[j];
        }
      }
      atomicAdd(&ssL[v], ssl);
    }
  }
  __syncthreads();
  if (tid < 64) atomicAdd(&stats1[tid], ssL[tid]);
}

__device__ void c2_body(int bid, const float* __restrict__ a,
    const void* __restrict__ tp, const void* __restrict__ w2a,
    const unsigned short* __restrict__ b2,
    void* __restrict__ out, float* __restrict__ stats2,
    const float* __restrict__ w222, char* smem)
{
  float* W2aL = (float*)smem;               // 128 f
  float* o2L  = (float*)(smem + 512);       // 1280 f
  float* ssL  = (float*)(smem + 5632);      // 32 f
  unsigned short* Hs = (unsigned short*)(smem + 5760);  // 320*32 bf16, rows 64B
  const int tid = threadIdx.x;
  const int n0 = bid * 64;
  for (int i = tid; i < 128; i += 256) W2aL[i] = ldf<true>(w2a, i);
  if (tid < 32) ssL[tid] = 0.f;
  float tp7 = ldf<true>(tp, 7), tp8 = ldf<true>(tp, 8), tp9 = ldf<true>(tp, 9), tp10 = ldf<true>(tp, 10);
  for (int idx = tid; idx < 1280; idx += 256){
    int n = idx / 20, r = idx - n*20, u = r / 5, m = r - u*5;
    float val = 0.f;
    if (n0 + n < NN){
      const float* an = a + (long)(n0 + n) * 9;
      float x1 = an[1], y1 = an[2], z1 = an[3];
      if (u == 0)      val = tp7 * an[0] * an[4 + m];
      else if (u == 1) val = tp8 * an[4 + m] * an[0];
      else if (u == 2){
        float pm;
        if (m == 0)      pm = 2.f*C_Hf*x1*z1;
        else if (m == 1) pm = 2.f*C_Hf*x1*y1;
        else if (m == 2) pm = C_S5f*y1*y1 - C_S5Hf*(x1*x1 + z1*z1);
        else if (m == 3) pm = 2.f*C_Hf*y1*z1;
        else             pm = C_Hf*(z1*z1 - x1*x1);
        val = tp9 * pm;
      } else {
        float q = 0.f;
        #pragma unroll
        for (int aa = 0; aa < 5; aa++){
          float sa = an[4 + aa];
          #pragma unroll
          for (int bb = 0; bb < 5; bb++) q += w222[aa*25 + bb*5 + m] * sa * an[4 + bb];
        }
        val = tp10 * q;
      }
    }
    o2L[idx] = val;
  }
  __syncthreads();
  {
    const int v = tid & 31, nb = tid >> 5;
    #pragma unroll
    for (int it = 0; it < 8; it++){
      int n = it*8 + nb;
      float h[5];
      #pragma unroll
      for (int m = 0; m < 5; m++){
        float s = 0.f;
        #pragma unroll
        for (int u = 0; u < 4; u++) s += o2L[n*20 + u*5 + m] * W2aL[u*32 + v];
        h[m] = s;
      }
      float g = sigf(sqrtf(h[0]*h[0] + h[1]*h[1] + h[2]*h[2] + h[3]*h[3] + h[4]*h[4]));
      #pragma unroll
      for (int m = 0; m < 5; m++){
        int r = m*64 + n;
        int byt = r*64 + ((v*2) ^ ((r&3)<<4));
        *(unsigned short*)((char*)Hs + byt) = f2bf(h[m]*g);
      }
    }
  }
  __syncthreads();
  const int lane = tid & 63, wv = tid >> 6;
  const int hi = lane >> 4, col = lane & 15;
  for (int mi = 0; mi < 5; mi++){
    int mt = wv*5 + mi;
    bf16x8 afr;
    {
      int row = mt*16 + (lane & 15);
      int byt = row*64 + ((hi*16) ^ ((row&3)<<4));
      afr = *(const bf16x8*)((const char*)Hs + byt);
    }
    int m = mt >> 2, nlb = (mt & 3)*16;
    for (int nt = 0; nt < 2; nt++){
      f32x4 acc = {0.f, 0.f, 0.f, 0.f};
      bf16x8 bfr = *(const bf16x8*)(b2 + ((long)nt*64 + lane)*8);
      acc = __builtin_amdgcn_mfma_f32_16x16x32_bf16(afr, bfr, acc, 0, 0, 0);
      int v = nt*16 + col;
      float ssl = 0.f;
      #pragma unroll
      for (int j = 0; j < 4; j++){
        int g = n0 + nlb + hi*4 + j;
        if (g < NN){
          stf<true>(out, (long)g*480 + 320 + v*5 + m, acc[j]);
          ssl += acc[j]*acc[j];
        }
      }
      atomicAdd(&ssL[v], ssl);
    }
  }
  __syncthreads();
  if (tid < 32) atomicAdd(&stats2[tid], ssL[tid]);
}

__global__ __launch_bounds__(256) void c_fused(const float* __restrict__ a,
    const void* __restrict__ tp, const void* __restrict__ w0a,
    const void* __restrict__ w1a, const void* __restrict__ w2a,
    const unsigned short* __restrict__ b0, const unsigned short* __restrict__ b1,
    const unsigned short* __restrict__ b2, const int* __restrict__ flag,
    void* __restrict__ out, float* __restrict__ stats,
    const float* __restrict__ w222)
{
  if (*flag == 0) return;  // f32 handled by fallback kernels
  __shared__ __align__(16) char smem[29056];
  const int b = blockIdx.x;
  if (b < NB_C)            c0_body(b,          a, tp, w0a, b0, out, stats,       smem);
  else if (b < 2*NB_C)     c1_body(b - NB_C,   a, tp, w1a, b1, out, stats + 256, smem);
  else                     c2_body(b - 2*NB_C, a, tp, w2a, b2, out, stats + 320, w222, smem);
}

// ===========================================================================
// f32 fallback c-kernels (insurance; early-exit on bf16 data)
// ===========================================================================
template<bool BF>
__global__ __launch_bounds__(256) void c0_kernel(const float* __restrict__ a,
    const void* __restrict__ tp, const void* __restrict__ w0a, const void* __restrict__ w0b,
    const int* __restrict__ flag, void* __restrict__ out, float* __restrict__ stats)
{
  if ((*flag != 0) != BF) return;
  __shared__ float W0aL[384];
  __shared__ float W0bL[16384];
  __shared__ float h0L[16*128];
  __shared__ float o0L[16*3];
  __shared__ float sumL[128], sqL[128];
  const int tid = threadIdx.x;
  const int c = tid & 127, half = tid >> 7;
  const int n0 = blockIdx.x * 16;
  for (int i = tid; i < 384; i += 256) W0aL[i] = ldf<BF>(w0a, i);
  for (int i = tid; i < 16384; i += 256) W0bL[i] = ldf<BF>(w0b, i);
  if (tid < 128){ sumL[tid] = 0.f; sqL[tid] = 0.f; }
  if (tid < 48){
    int n = tid / 3, j = tid - n*3;
    const float* an = a + (long)(n0 + n) * 9;
    float tpj = ldf<BF>(tp, j);
    float v;
    if (j == 0)      v = tpj * an[0]*an[0];
    else if (j == 1) v = tpj * (an[1]*an[1] + an[2]*an[2] + an[3]*an[3]) * INV_SQ3f;
    else             v = tpj * (an[4]*an[4] + an[5]*an[5] + an[6]*an[6] + an[7]*an[7] + an[8]*an[8]) * INV_SQ5f;
    o0L[tid] = v;
  }
  __syncthreads();
  #pragma unroll
  for (int i = 0; i < 8; i++){
    int n = half*8 + i;
    float pre = o0L[n*3]*W0aL[c] + o0L[n*3+1]*W0aL[128+c] + o0L[n*3+2]*W0aL[256+c];
    h0L[n*128 + c] = sigf(pre);
  }
  __syncthreads();
  float acc[8];
  #pragma unroll
  for (int i = 0; i < 8; i++) acc[i] = 0.f;
  for (int k = 0; k < 128; k++){
    float w = W0bL[k*128 + c];
    #pragma unroll
    for (int i = 0; i < 8; i++) acc[i] += h0L[(half*8 + i)*128 + k] * w;
  }
  float lsum = 0.f, lsq = 0.f;
  #pragma unroll
  for (int i = 0; i < 8; i++){
    int n = half*8 + i;
    stf<BF>(out, (long)(n0 + n)*480 + c, acc[i]);
    lsum += acc[i]; lsq += acc[i]*acc[i];
  }
  atomicAdd(&sumL[c], lsum); atomicAdd(&sqL[c], lsq);
  __syncthreads();
  if (tid < 128){ atomicAdd(&stats[tid], sumL[tid]); atomicAdd(&stats[128 + tid], sqL[tid]); }
}

template<bool BF>
__global__ __launch_bounds__(256) void c1_kernel(const float* __restrict__ a,
    const void* __restrict__ tp, const void* __restrict__ w1a, const void* __restrict__ w1b,
    const int* __restrict__ flag, void* __restrict__ out, float* __restrict__ stats1)
{
  if ((*flag != 0) != BF) return;
  __shared__ float W1aL[256];
  __shared__ float W1bL[4096];
  __shared__ float h1L[32*64*3];
  __shared__ float o1L[32*12];
  __shared__ float ssL[64];
  const int tid = threadIdx.x;
  const int v = tid & 63, ng = tid >> 6;
  const int n0 = blockIdx.x * 32;
  for (int i = tid; i < 256; i += 256) W1aL[i] = ldf<BF>(w1a, i);
  for (int i = tid; i < 4096; i += 256) W1bL[i] = ldf<BF>(w1b, i);
  if (tid < 64) ssL[tid] = 0.f;
  float tp3 = ldf<BF>(tp, 3), tp4 = ldf<BF>(tp, 4), tp5 = ldf<BF>(tp, 5), tp6 = ldf<BF>(tp, 6);
  for (int idx = tid; idx < 384; idx += 256){
    int n = idx / 12, r = idx - n*12;
    int u = r / 3, m = r - u*3;
    const float* an = a + (long)(n0 + n) * 9;
    float s1x = an[1], s1y = an[2], s1z = an[3];
    float val;
    if (u == 0)      val = tp3 * an[0] * an[1 + m];
    else if (u == 1) val = tp4 * an[1 + m] * an[0];
    else {
      float e1m;
      if (m == 0)      e1m = C_Hf*(an[4]*s1z + an[5]*s1y - an[8]*s1x) - C_S5Hf*an[6]*s1x;
      else if (m == 1) e1m = C_Hf*(an[5]*s1x + an[7]*s1z) + C_S5f*an[6]*s1y;
      else             e1m = C_Hf*(an[4]*s1x + an[7]*s1y + an[8]*s1z) - C_S5Hf*an[6]*s1z;
      val = (u == 2 ? tp5 : tp6) * e1m;
    }
    o1L[idx] = val;
  }
  __syncthreads();
  #pragma unroll
  for (int i = 0; i < 8; i++){
    int n = ng*8 + i;
    float h[3];
    #pragma unroll
    for (int m = 0; m < 3; m++){
      float s = 0.f;
      #pragma unroll
      for (int u = 0; u < 4; u++) s += o1L[n*12 + u*3 + m] * W1aL[u*64 + v];
      h[m] = s;
    }
    float g = sigf(sqrtf(h[0]*h[0] + h[1]*h[1] + h[2]*h[2]));
    int b = (n*64 + v)*3;
    h1L[b] = h[0]*g; h1L[b+1] = h[1]*g; h1L[b+2] = h[2]*g;
  }
  __syncthreads();
  float ss = 0.f;
  for (int i = 0; i < 8; i++){
    int n = ng*8 + i;
    float a0 = 0.f, a1 = 0.f, a2 = 0.f;
    for (int u = 0; u < 64; u++){
      float w = W1bL[u*64 + v];
      const float* hp = &h1L[(n*64 + u)*3];
      a0 += hp[0]*w; a1 += hp[1]*w; a2 += hp[2]*w;
    }
    long b = (long)(n0 + n)*480 + 128 + v*3;
    stf<BF>(out, b, a0); stf<BF>(out, b+1, a1); stf<BF>(out, b+2, a2);
    ss += a0*a0 + a1*a1 + a2*a2;
  }
  atomicAdd(&ssL[v], ss);
  __syncthreads();
  if (tid < 64) atomicAdd(&stats1[tid], ssL[tid]);
}

template<bool BF>
__global__ __launch_bounds__(256) void c2_kernel(const float* __restrict__ a,
    const void* __restrict__ tp, const void* __restrict__ w2a, const void* __restrict__ w2b,
    const int* __restrict__ flag, void* __restrict__ out, float* __restrict__ stats2,
    const float* __restrict__ w222)
{
  if ((*flag != 0) != BF) return;
  __shared__ float W2aL[128];
  __shared__ float W2bL[1024];
  __shared__ float h2L[32*32*5];
  __shared__ float o2L[32*20];
  __shared__ float ssL[32];
  const int tid = threadIdx.x;
  const int v = tid & 31, ng = tid >> 5;
  const int n0 = blockIdx.x * 32;
  for (int i = tid; i < 128; i += 256) W2aL[i] = ldf<BF>(w2a, i);
  for (int i = tid; i < 1024; i += 256) W2bL[i] = ldf<BF>(w2b, i);
  if (tid < 32) ssL[tid] = 0.f;
  float tp7 = ldf<BF>(tp, 7), tp8 = ldf<BF>(tp, 8), tp9 = ldf<BF>(tp, 9), tp10 = ldf<BF>(tp, 10);
  for (int idx = tid; idx < 640; idx += 256){
    int n = idx / 20, r = idx - n*20, u = r / 5, m = r - u*5;
    const float* an = a + (long)(n0 + n) * 9;
    float x1 = an[1], y1 = an[2], z1 = an[3];
    float val;
    if (u == 0)      val = tp7 * an[0] * an[4 + m];
    else if (u == 1) val = tp8 * an[4 + m] * an[0];
    else if (u == 2){
      float pm;
      if (m == 0)      pm = 2.f*C_Hf*x1*z1;
      else if (m == 1) pm = 2.f*C_Hf*x1*y1;
      else if (m == 2) pm = C_S5f*y1*y1 - C_S5Hf*(x1*x1 + z1*z1);
      else if (m == 3) pm = 2.f*C_Hf*y1*z1;
      else             pm = C_Hf*(z1*z1 - x1*x1);
      val = tp9 * pm;
    } else {
      float q = 0.f;
      #pragma unroll
      for (int aa = 0; aa < 5; aa++){
        float sa = an[4 + aa];
        #pragma unroll
        for (int bb = 0; bb < 5; bb++) q += w222[aa*25 + bb*5 + m] * sa * an[4 + bb];
      }
      val = tp10 * q;
    }
    o2L[idx] = val;
  }
  __syncthreads();
  #pragma unroll
  for (int i = 0; i < 4; i++){
    int n = ng*4 + i;
    float h[5];
    #pragma unroll
    for (int m = 0; m < 5; m++){
      float s = 0.f;
      #pragma unroll
      for (int u = 0; u < 4; u++) s += o2L[n*20 + u*5 + m] * W2aL[u*32 + v];
      h[m] = s;
    }
    float g = sigf(sqrtf(h[0]*h[0] + h[1]*h[1] + h[2]*h[2] + h[3]*h[3] + h[4]*h[4]));
    int b = (n*32 + v)*5;
    #pragma unroll
    for (int m = 0; m < 5; m++) h2L[b + m] = h[m]*g;
  }
  __syncthreads();
  float ss = 0.f;
  #pragma unroll
  for (int i = 0; i < 4; i++){
    int n = ng*4 + i;
    float acc[5] = {0.f, 0.f, 0.f, 0.f, 0.f};
    for (int u = 0; u < 32; u++){
      float w = W2bL[u*32 + v];
      const float* hp = &h2L[(n*32 + u)*5];
      #pragma unroll
      for (int m = 0; m < 5; m++) acc[m] += hp[m]*w;
    }
    long b = (long)(n0 + n)*480 + 320 + v*5;
    #pragma unroll
    for (int m = 0; m < 5; m++) stf<BF>(out, b + m, acc[m]);
    #pragma unroll
    for (int m = 0; m < 5; m++) ss += acc[m]*acc[m];
  }
  atomicAdd(&ssL[v], ss);
  __syncthreads();
  if (tid < 32) atomicAdd(&stats2[tid], ssL[tid]);
}

// ---------------------------------------------------------------------------
// finalize: per-channel scale/bias table (480 each) for the fused norm pass.
// ---------------------------------------------------------------------------
__global__ void finalize_kernel(const float* __restrict__ stats, float* __restrict__ params){
  int t = threadIdx.x;
  if (t >= 480) return;
  float sc, bi = 0.f;
  if (t < 128){
    float mean = stats[t] * (1.0f/NN);
    float var  = stats[128 + t] * (1.0f/NN) - mean*mean;
    sc = 1.0f / sqrtf(fmaxf(var, 0.f) + EPSf);
    bi = -mean * sc;
  } else if (t < 320){
    int v = (t - 128) / 3;
    sc = 1.0f / sqrtf(stats[256 + v] * (1.0f/(NN*3.0f)) + EPSf);
  } else {
    int v = (t - 320) / 5;
    sc = 1.0f / sqrtf(stats[320 + v] * (1.0f/(NN*5.0f)) + EPSf);
  }
  params[t] = sc;
  params[480 + t] = bi;
}

// ---------------------------------------------------------------------------
// norm: thread t owns channel-pair (2t,2t+1); blocks stride over node rows.
// No modulo, scale/bias hoisted to registers, fully coalesced row access.
// ---------------------------------------------------------------------------
__global__ __launch_bounds__(256) void norm_kernel(const int* __restrict__ flag,
    void* __restrict__ out, const float* __restrict__ params)
{
  const int t = threadIdx.x;
  if (t >= 240) return;
  const int j = t*2;
  const float sc0 = params[j], sc1 = params[j+1];
  const float bi0 = params[480+j], bi1 = params[480+j+1];
  const bool bf = (*flag != 0);
  if (bf){
    unsigned int* o = (unsigned int*)out;
    for (long n = blockIdx.x; n < NN; n += gridDim.x){
      long idx = n*240 + t;
      unsigned int w = o[idx];
      float r0 = bf2f((unsigned short)(w & 0xffffu)) * sc0 + bi0;
      float r1 = bf2f((unsigned short)(w >> 16))     * sc1 + bi1;
      o[idx] = (unsigned)f2bf(r0) | ((unsigned)f2bf(r1) << 16);
    }
  } else {
    float2* o = (float2*)out;
    for (long n = blockIdx.x; n < NN; n += gridDim.x){
      long idx = n*240 + t;
      float2 w = o[idx];
      o[idx] = make_float2(w.x * sc0 + bi0, w.y * sc1 + bi1);
    }
  }
}

// ---------------------------------------------------------------------------
extern "C" void kernel_launch(void* const* d_in, const int* in_sizes, int n_in,
                              void* d_out, int out_size, void* d_ws, size_t ws_size,
                              hipStream_t stream) {
  const void* x   = d_in[0];
  const void* pos = d_in[1];
  const int*  ei  = (const int*)d_in[2];
  const void* tp  = d_in[3];
  const void* w0a = d_in[4];
  const void* w1a = d_in[5];
  const void* w2a = d_in[6];
  const void* w0b = d_in[7];
  const void* w1b = d_in[8];
  const void* w2b = d_in[9];

  // ws layout: [0,4) flag | [64, 400064) cnt (NN int) | [400064, 4000064) a (NN*9 f32)
  //          | [4000064,...) stats(352) | params(960) | w222(125) | bfrag packs
  int*   flag   = (int*)d_ws;
  int*   cnt    = (int*)((char*)d_ws + 64);
  float* a      = (float*)((char*)d_ws + 400064);
  float* stats  = (float*)((char*)d_ws + 4000064);
  float* params = stats + 352;
  float* w222   = params + 960;
  unsigned short* b0 = (unsigned short*)((char*)d_ws + 4006016);
  unsigned short* b1 = b0 + 16384;
  unsigned short* b2 = b1 + 4096;

  // CSR scratch lives in d_out's node region (32MB < node region), overwritten later.
  int* csr = (int*)d_out;

  hipMemsetAsync(d_ws, 0, 4001472, stream);
  setup_kernel<<<1, 256, 0, stream>>>(x, flag, w222, w0b, w1b, w2b, b0, b1, b2);

  edge_kernel<<<NE/256, 256, 0, stream>>>(x, pos, ei, flag, cnt, csr, a, d_out);
  agg_kernel <<<NN/8,   256, 0, stream>>>(x, pos, flag, cnt, csr, a);

  // bf16 path: fused MFMA kernel (c0 | c1 | c2 by block range)
  c_fused<<<3*NB_C, 256, 0, stream>>>(a, tp, w0a, w1a, w2a, b0, b1, b2, flag,
                                      d_out, stats, w222);

  // f32 fallback path (early-exits when bf16)
  c0_kernel<false><<<NN/16, 256, 0, stream>>>(a, tp, w0a, w0b, flag, d_out, stats);
  c1_kernel<false><<<NN/32, 256, 0, stream>>>(a, tp, w1a, w1b, flag, d_out, stats + 256);
  c2_kernel<false><<<NN/32, 256, 0, stream>>>(a, tp, w2a, w2b, flag, d_out, stats + 320, w222);

  finalize_kernel<<<1, 512, 0, stream>>>(stats, params);

  norm_kernel<<<2048, 256, 0, stream>>>(flag, d_out, params);
}